// Round 7
// baseline (1842.392 us; speedup 1.0000x reference)
//
#include <hip/hip_runtime.h>
#include <math.h>

// Problem constants
#define B_   4
#define N_   2048
#define D_   1024
#define H_   16
#define d_   64
#define F_   2048
#define PAD_ 8192
#define FB_  4097
#define NC_  32
#define EPS_ 1e-6f
#define PI_F 3.14159265358979323846f
#define PI_D 3.14159265358979323846

typedef unsigned short ushort_t;
typedef short bf16x8 __attribute__((ext_vector_type(8)));
typedef float f32x4  __attribute__((ext_vector_type(4)));

#define GLD16(gp, lp) __builtin_amdgcn_global_load_lds( \
    (const __attribute__((address_space(1))) unsigned int*)(const void*)(gp), \
    (__attribute__((address_space(3))) unsigned int*)(void*)(lp), 16, 0, 0)

// round-to-nearest-even fp32 -> bf16 (bits), plus residual split
__device__ __forceinline__ ushort_t bf16_rne(float v) {
    unsigned b = __float_as_uint(v);
    unsigned rb = b + 0x7fffu + ((b >> 16) & 1u);
    return (ushort_t)(rb >> 16);
}
__device__ __forceinline__ void split_bf16(float v, ushort_t& h, ushort_t& l) {
    h = bf16_rne(v);
    float fh = __uint_as_float((unsigned)h << 16);
    l = bf16_rne(v - fh);
}

__device__ __forceinline__ float2 cmul(float2 a, float2 w) {
    return make_float2(a.x * w.x - a.y * w.y, a.x * w.y + a.y * w.x);
}
__device__ __forceinline__ float2 cmulc(float2 a, float2 w) {   // a * conj(w)
    return make_float2(a.x * w.x + a.y * w.y, a.y * w.x - a.x * w.y);
}

// ---------------------------------------------------------------------------
// Merged twiddle builder: radix-2 table (13*4096) then radix-4 table (6*3072)
// ---------------------------------------------------------------------------
__global__ __launch_bounds__(256) void kern_twid(float2* __restrict__ twid,
                                                 float2* __restrict__ tw4) {
    int idx = blockIdx.x * 256 + threadIdx.x;
    if (idx < 13 * 4096) {
        const int lh = idx >> 12, t = idx & 4095;
        const int hh = 1 << lh;
        const int j = t & (hh - 1);
        double s, c;
        sincos(-PI_D * (double)j / (double)hh, &s, &c);
        twid[idx] = make_float2((float)c, (float)s);
    } else {
        idx -= 13 * 4096;
        if (idx < 6 * 3072) {
            const int s = idx / 3072;
            const int r = idx - s * 3072;
            const int j = r / 3;
            const int m = r - 3 * j + 1;
            const int q = 1024 >> (2 * s);
            double sn, cs;
            sincos(-2.0 * PI_D * (double)(m * (j & (q - 1))) / (double)(4 * q), &sn, &cs);
            tw4[idx] = make_float2((float)cs, (float)sn);
        }
    }
}

// ---------------------------------------------------------------------------
// Merged split: three fp32 arrays -> (hi, lo) bf16 arrays in one launch
// ---------------------------------------------------------------------------
__global__ __launch_bounds__(256) void kern_split3(
        const float* __restrict__ s0, ushort_t* __restrict__ h0, ushort_t* __restrict__ l0, int n0,
        const float* __restrict__ s1, ushort_t* __restrict__ h1, ushort_t* __restrict__ l1, int n1,
        const float* __restrict__ s2, ushort_t* __restrict__ h2, ushort_t* __restrict__ l2, int n2) {
    int i = blockIdx.x * 256 + threadIdx.x;
    const float* s; ushort_t* hh; ushort_t* ll; int k;
    if (i < n0)                { s = s0; hh = h0; ll = l0; k = i; }
    else if (i < n0 + n1)      { s = s1; hh = h1; ll = l1; k = i - n0; }
    else if (i < n0 + n1 + n2) { s = s2; hh = h2; ll = l2; k = i - n0 - n1; }
    else return;
    ushort_t h, l;
    split_bf16(s[k], h, l);
    hh[k] = h; ll[k] = l;
}

// ---------------------------------------------------------------------------
// Split-bf16 MFMA NT GEMM: C = A*B^T + bias. 3 cross-products.
// 128x128 tile, BK=32, 256 thr. M, Nn, K multiples of 128.
// ---------------------------------------------------------------------------
__global__ __launch_bounds__(256) void gemm_mfma(
        const ushort_t* __restrict__ Ah, const ushort_t* __restrict__ Al, int lda,
        const ushort_t* __restrict__ Bh, const ushort_t* __restrict__ Bl, int ldb,
        const float* __restrict__ bias, float* __restrict__ C,
        int Nn, int K) {
    __shared__ __align__(16) ushort_t At0[128 * 32];
    __shared__ __align__(16) ushort_t At1[128 * 32];
    __shared__ __align__(16) ushort_t Bt0[128 * 32];
    __shared__ __align__(16) ushort_t Bt1[128 * 32];

    const int tid = threadIdx.x;
    const int wv = tid >> 6, lane = tid & 63;
    const int quad = lane >> 4, lrow = lane & 15;
    const int m0 = blockIdx.y * 128, n0 = blockIdx.x * 128;
    const int mw = (wv >> 1) * 64, nw = (wv & 1) * 64;

    const int srow = lane >> 2;
    const int schunk = (lane & 3) * 8;

    f32x4 acc[4][4] = {};

    for (int k0 = 0; k0 < K; k0 += 32) {
        {
            const size_t ga = (size_t)(m0 + wv * 32 + srow) * lda + k0 + schunk;
            const size_t gb = (size_t)(n0 + wv * 32 + srow) * ldb + k0 + schunk;
            const size_t ga2 = ga + (size_t)16 * lda;
            const size_t gb2 = gb + (size_t)16 * ldb;
            GLD16(Ah + ga,  &At0[(wv * 32) * 32]);
            GLD16(Ah + ga2, &At0[(wv * 32 + 16) * 32]);
            GLD16(Al + ga,  &At1[(wv * 32) * 32]);
            GLD16(Al + ga2, &At1[(wv * 32 + 16) * 32]);
            GLD16(Bh + gb,  &Bt0[(wv * 32) * 32]);
            GLD16(Bh + gb2, &Bt0[(wv * 32 + 16) * 32]);
            GLD16(Bl + gb,  &Bt1[(wv * 32) * 32]);
            GLD16(Bl + gb2, &Bt1[(wv * 32 + 16) * 32]);
        }
        __syncthreads();

        bf16x8 a0[4], a1[4], b0[4], b1[4];
#pragma unroll
        for (int i = 0; i < 4; ++i) {
            a0[i] = *(const bf16x8*)&At0[(mw + i * 16 + lrow) * 32 + quad * 8];
            a1[i] = *(const bf16x8*)&At1[(mw + i * 16 + lrow) * 32 + quad * 8];
            b0[i] = *(const bf16x8*)&Bt0[(nw + i * 16 + lrow) * 32 + quad * 8];
            b1[i] = *(const bf16x8*)&Bt1[(nw + i * 16 + lrow) * 32 + quad * 8];
        }
#pragma unroll
        for (int mi = 0; mi < 4; ++mi)
#pragma unroll
            for (int nj = 0; nj < 4; ++nj) {
                acc[mi][nj] = __builtin_amdgcn_mfma_f32_16x16x32_bf16(a0[mi], b0[nj], acc[mi][nj], 0, 0, 0);
                acc[mi][nj] = __builtin_amdgcn_mfma_f32_16x16x32_bf16(a0[mi], b1[nj], acc[mi][nj], 0, 0, 0);
                acc[mi][nj] = __builtin_amdgcn_mfma_f32_16x16x32_bf16(a1[mi], b0[nj], acc[mi][nj], 0, 0, 0);
            }
        __syncthreads();
    }

#pragma unroll
    for (int mi = 0; mi < 4; ++mi) {
        const int row = m0 + mw + mi * 16 + quad * 4;
#pragma unroll
        for (int nj = 0; nj < 4; ++nj) {
            const int col = n0 + nw + nj * 16 + lrow;
            const float bv = bias[col];
#pragma unroll
            for (int r = 0; r < 4; ++r)
                C[(size_t)(row + r) * Nn + col] = acc[mi][nj][r] + bv;
        }
    }
}

// ---------------------------------------------------------------------------
// Generic fp32 NT GEMM (only the tiny M=4 control GEMMs).
// ---------------------------------------------------------------------------
__device__ __forceinline__ float gelu_f(float x) {
    return 0.5f * x * (1.f + tanhf(0.7978845608028654f * (x + 0.044715f * x * x * x)));
}

__global__ __launch_bounds__(256) void gemm_nt(const float* __restrict__ A,
                                               const float* __restrict__ Bm,
                                               const float* __restrict__ bias,
                                               float* __restrict__ C,
                                               int M, int Nn, int K, int lda, int act) {
    __shared__ float As[16][64];
    __shared__ float Bs[16][64];
    const int tid = threadIdx.x;
    const int tx = tid & 15, ty = tid >> 4;
    const int m0 = blockIdx.y * 64, n0 = blockIdx.x * 64;

    float acc[4][4];
#pragma unroll
    for (int i = 0; i < 4; ++i)
#pragma unroll
        for (int j = 0; j < 4; ++j) acc[i][j] = 0.f;

    const int lr = tid >> 2;
    const int lk = (tid & 3) * 4;

    for (int k0 = 0; k0 < K; k0 += 16) {
        float4 av = make_float4(0.f, 0.f, 0.f, 0.f);
        float4 bv = make_float4(0.f, 0.f, 0.f, 0.f);
        if (m0 + lr < M)
            av = *(const float4*)(A + (size_t)(m0 + lr) * lda + k0 + lk);
        if (n0 + lr < Nn)
            bv = *(const float4*)(Bm + (size_t)(n0 + lr) * K + k0 + lk);
        As[lk + 0][lr] = av.x; As[lk + 1][lr] = av.y;
        As[lk + 2][lr] = av.z; As[lk + 3][lr] = av.w;
        Bs[lk + 0][lr] = bv.x; Bs[lk + 1][lr] = bv.y;
        Bs[lk + 2][lr] = bv.z; Bs[lk + 3][lr] = bv.w;
        __syncthreads();
#pragma unroll
        for (int k = 0; k < 16; ++k) {
            float a[4], b[4];
#pragma unroll
            for (int i = 0; i < 4; ++i) a[i] = As[k][ty * 4 + i];
#pragma unroll
            for (int j = 0; j < 4; ++j) b[j] = Bs[k][tx * 4 + j];
#pragma unroll
            for (int i = 0; i < 4; ++i)
#pragma unroll
                for (int j = 0; j < 4; ++j) acc[i][j] += a[i] * b[j];
        }
        __syncthreads();
    }
#pragma unroll
    for (int i = 0; i < 4; ++i) {
        int row = m0 + ty * 4 + i;
        if (row >= M) continue;
#pragma unroll
        for (int j = 0; j < 4; ++j) {
            int col = n0 + tx * 4 + j;
            if (col >= Nn) continue;
            float v = acc[i][j] + bias[col];
            if (act == 1) v = gelu_f(v);
            C[(size_t)row * Nn + col] = v;
        }
    }
}

// ---------------------------------------------------------------------------
// Featuremap + field build. Tiles padded to [68] (16B-aligned rows) for
// float4 broadcast LDS reads; wbuf stays [65] (transposed store pattern).
// ---------------------------------------------------------------------------
__global__ __launch_bounds__(256) void kern_feat(float* __restrict__ qkvg,
                                                 const float* __restrict__ qfm_w,
                                                 const float* __restrict__ qfm_b,
                                                 const float* __restrict__ kfm_w,
                                                 const float* __restrict__ kfm_b,
                                                 const float* __restrict__ wg_w,
                                                 const float* __restrict__ wg_b,
                                                 float* __restrict__ field) {
    __shared__ __align__(16) float in_t[64][68];
    __shared__ __align__(16) float tmp[64][68];
    __shared__ float wbuf[64][65];
    __shared__ float bsm[64];
    __shared__ float wsm[64];
    __shared__ float wgbuf[64];

    const int tid = threadIdx.x;
    const int lane = tid & 63, grp = tid >> 6;
    const int n0 = blockIdx.x * 64;
    const int h = blockIdx.y, b = blockIdx.z;
    const size_t rowbase = (size_t)(b * N_ + n0) * 4096;

    const int lr4 = tid >> 4;          // 0..15 row within 16-row group
    const int lc4 = (tid & 15) * 4;    // 0,4,...,60 col

#define LOAD64x64(dst, off) \
    for (int it = 0; it < 4; ++it) { \
        int r = lr4 + it * 16; \
        float4 v = *(const float4*)&qkvg[rowbase + (size_t)r * 4096 + (off) + lc4]; \
        *(float4*)&dst[r][lc4] = v; \
    }

#define MLP_LAYER(dstarr, srcarr) { \
    const int j = lane, ibase = grp * 16; \
    float acc[16]; \
    _Pragma("unroll") for (int ii = 0; ii < 16; ++ii) acc[ii] = 0.f; \
    for (int c4 = 0; c4 < 64; c4 += 4) { \
        float w0 = wbuf[c4 + 0][j], w1 = wbuf[c4 + 1][j]; \
        float w2 = wbuf[c4 + 2][j], w3 = wbuf[c4 + 3][j]; \
        _Pragma("unroll") for (int ii = 0; ii < 16; ++ii) { \
            float4 iv = *(const float4*)&srcarr[ibase + ii][c4]; \
            acc[ii] += iv.x * w0 + iv.y * w1 + iv.z * w2 + iv.w * w3; \
        } \
    } \
    float bj = bsm[j]; \
    _Pragma("unroll") for (int ii = 0; ii < 16; ++ii) \
        dstarr[ibase + ii][j] = fmaxf(acc[ii] + bj, 0.f); \
    }

    // ============ K path ============
    LOAD64x64(in_t, D_ + h * 64)
    for (int it = 0; it < 16; ++it) {
        int r = grp + 4 * it;
        wbuf[lane][r] = kfm_w[(size_t)r * 64 + lane];   // wbuf[c][j] = W0[j][c]
    }
    if (tid < 64) { bsm[tid] = kfm_b[tid]; wsm[tid] = wg_w[tid]; }
    __syncthreads();
    if (tid < 64) {   // wg from raw k
        float s = 0.f;
        for (int c4 = 0; c4 < 64; c4 += 4) {
            float4 iv = *(const float4*)&in_t[tid][c4];
            s += iv.x * wsm[c4] + iv.y * wsm[c4 + 1] + iv.z * wsm[c4 + 2] + iv.w * wsm[c4 + 3];
        }
        s += wg_b[0];
        wgbuf[tid] = 1.f / (1.f + expf(-s));
    }
    MLP_LAYER(tmp, in_t)
    __syncthreads();
    for (int it = 0; it < 16; ++it) {
        int r = grp + 4 * it;
        wbuf[lane][r] = kfm_w[(size_t)(64 + r) * 64 + lane];
    }
    if (tid < 64) bsm[tid] = kfm_b[64 + tid];
    __syncthreads();
    {   // L2: phi_k -> in_t (+EPS)
        const int j = lane, ibase = grp * 16;
        float acc[16];
#pragma unroll
        for (int ii = 0; ii < 16; ++ii) acc[ii] = 0.f;
        for (int c4 = 0; c4 < 64; c4 += 4) {
            float w0 = wbuf[c4 + 0][j], w1 = wbuf[c4 + 1][j];
            float w2 = wbuf[c4 + 2][j], w3 = wbuf[c4 + 3][j];
#pragma unroll
            for (int ii = 0; ii < 16; ++ii) {
                float4 iv = *(const float4*)&tmp[ibase + ii][c4];
                acc[ii] += iv.x * w0 + iv.y * w1 + iv.z * w2 + iv.w * w3;
            }
        }
        float bj = bsm[j];
#pragma unroll
        for (int ii = 0; ii < 16; ++ii)
            in_t[ibase + ii][j] = fmaxf(acc[ii] + bj, 0.f) + EPS_;
    }
    __syncthreads();
    LOAD64x64(tmp, 2 * D_ + h * 64)     // V -> tmp
    __syncthreads();

    // field write: write[c<64] = wg*pk*v ; write[c>=64] = wg*pk
    {
        float* frow = field + (size_t)(b * H_ + h) * 128 * F_;
        const bool last = (n0 == N_ - 64);
        for (int c = grp; c < 128; c += 4) {
            int i = lane;
            float v = (c < 64) ? wgbuf[i] * in_t[i][c] * tmp[i][c]
                               : wgbuf[i] * in_t[i][c - 64];
            if (last) {
                if (i == 62) {
                    float v2 = (c < 64) ? wgbuf[63] * in_t[63][c] * tmp[63][c]
                                        : wgbuf[63] * in_t[63][c - 64];
                    v += v2;
                } else if (i == 63) v = 0.f;
            }
            frow[(size_t)c * F_ + n0 + i] = v;
        }
    }
    __syncthreads();

    // ============ Q path ============
    LOAD64x64(in_t, h * 64)
    for (int it = 0; it < 16; ++it) {
        int r = grp + 4 * it;
        wbuf[lane][r] = qfm_w[(size_t)r * 64 + lane];
    }
    if (tid < 64) bsm[tid] = qfm_b[tid];
    __syncthreads();
    MLP_LAYER(tmp, in_t)
    __syncthreads();
    for (int it = 0; it < 16; ++it) {
        int r = grp + 4 * it;
        wbuf[lane][r] = qfm_w[(size_t)(64 + r) * 64 + lane];
    }
    if (tid < 64) bsm[tid] = qfm_b[64 + tid];
    __syncthreads();
    {   // L2: phi_q -> qkvg k-columns
        const int j = lane, ibase = grp * 16;
        float acc[16];
#pragma unroll
        for (int ii = 0; ii < 16; ++ii) acc[ii] = 0.f;
        for (int c4 = 0; c4 < 64; c4 += 4) {
            float w0 = wbuf[c4 + 0][j], w1 = wbuf[c4 + 1][j];
            float w2 = wbuf[c4 + 2][j], w3 = wbuf[c4 + 3][j];
#pragma unroll
            for (int ii = 0; ii < 16; ++ii) {
                float4 iv = *(const float4*)&tmp[ibase + ii][c4];
                acc[ii] += iv.x * w0 + iv.y * w1 + iv.z * w2 + iv.w * w3;
            }
        }
        float bj = bsm[j];
#pragma unroll
        for (int ii = 0; ii < 16; ++ii) {
            float v = fmaxf(acc[ii] + bj, 0.f) + EPS_;
            qkvg[rowbase + (size_t)(ibase + ii) * 4096 + D_ + h * 64 + j] = v;
        }
    }
#undef LOAD64x64
#undef MLP_LAYER
}

// ---------------------------------------------------------------------------
// LayerNorm of q token 0 -> q0n (B x 1024).
// ---------------------------------------------------------------------------
__global__ void kern_ln(const float* __restrict__ qkvg,
                        const float* __restrict__ ln_g,
                        const float* __restrict__ ln_b,
                        float* __restrict__ q0n) {
    const int bh = blockIdx.x, c = threadIdx.x;
    const int b = bh >> 4, h = bh & 15;
    float x = qkvg[(size_t)(b * N_) * 4096 + h * 64 + c];
    float mu = x;
    for (int m = 1; m < 64; m <<= 1) mu += __shfl_xor(mu, m);
    mu *= (1.f / 64.f);
    float dv = (x - mu) * (x - mu);
    for (int m = 1; m < 64; m <<= 1) dv += __shfl_xor(dv, m);
    float var = dv * (1.f / 64.f);
    q0n[b * 1024 + h * 64 + c] = (x - mu) * rsqrtf(var + 1e-5f) * ln_g[c] + ln_b[c];
}

// ---------------------------------------------------------------------------
// Templated table-driven FFT helpers (NT = threads per block).
// ---------------------------------------------------------------------------
template <int NT>
__device__ __forceinline__ void fft_fwd_dif_t(float* xr, float* xi, int tid, int logn,
                                              const float2* __restrict__ twid) {
    const int nb = 1 << (logn - 1);
    for (int lh = logn - 1; lh >= 0; --lh) {
        const int hh = 1 << lh;
        const float2* tws = twid + lh * 4096;
        for (int t = tid; t < nb; t += NT) {
            int j = t & (hh - 1);
            int i1 = ((t >> lh) << (lh + 1)) | j;
            int i2 = i1 + hh;
            float2 tw = tws[t];
            float ar = xr[i1], ai = xi[i1];
            float br = xr[i2], bi = xi[i2];
            xr[i1] = ar + br; xi[i1] = ai + bi;
            float tr = ar - br, ti = ai - bi;
            xr[i2] = tr * tw.x - ti * tw.y;
            xi[i2] = tr * tw.y + ti * tw.x;
        }
        __syncthreads();
    }
}

template <int NT>
__device__ __forceinline__ void fft_inv_dit_t(float* xr, float* xi, int tid, int logn,
                                              const float2* __restrict__ twid) {
    const int nb = 1 << (logn - 1);
    for (int lh = 0; lh < logn; ++lh) {
        const int hh = 1 << lh;
        const float2* tws = twid + lh * 4096;
        for (int t = tid; t < nb; t += NT) {
            int j = t & (hh - 1);
            int i1 = ((t >> lh) << (lh + 1)) | j;
            int i2 = i1 + hh;
            float2 tw = tws[t];   // conj applied
            float br = xr[i2], bi = xi[i2];
            float tr = br * tw.x + bi * tw.y;
            float ti = bi * tw.x - br * tw.y;
            float ar = xr[i1], ai = xi[i1];
            xr[i1] = ar + tr; xi[i1] = ai + ti;
            xr[i2] = ar - tr; xi[i2] = ai - ti;
        }
        __syncthreads();
    }
}

template <int NT>
__device__ __forceinline__ void fft4_fwd(float2* z, int tid,
                                         const float2* __restrict__ tw4) {
#pragma unroll
    for (int s = 0; s < 6; ++s) {
        const int q = 1024 >> (2 * s);
        const float2* tws = tw4 + s * 3072;
        for (int t = tid; t < 1024; t += NT) {
            int j = t & (q - 1);
            int base = ((t & ~(q - 1)) << 2) | j;
            float2 a = z[base], b = z[base + q], c = z[base + 2 * q], d = z[base + 3 * q];
            float2 s0 = make_float2(a.x + c.x, a.y + c.y);
            float2 s1 = make_float2(a.x - c.x, a.y - c.y);
            float2 s2 = make_float2(b.x + d.x, b.y + d.y);
            float2 s3 = make_float2(b.x - d.x, b.y - d.y);
            float2 m1 = make_float2(s1.x + s3.y, s1.y - s3.x);
            float2 m2 = make_float2(s0.x - s2.x, s0.y - s2.y);
            float2 m3 = make_float2(s1.x - s3.y, s1.y + s3.x);
            z[base]         = make_float2(s0.x + s2.x, s0.y + s2.y);
            z[base + q]     = cmul(m1, tws[3 * j + 0]);
            z[base + 2 * q] = cmul(m2, tws[3 * j + 1]);
            z[base + 3 * q] = cmul(m3, tws[3 * j + 2]);
        }
        __syncthreads();
    }
}

template <int NT>
__device__ __forceinline__ void fft4_inv(float2* z, int tid,
                                         const float2* __restrict__ tw4) {
#pragma unroll
    for (int s = 5; s >= 0; --s) {
        const int q = 1024 >> (2 * s);
        const float2* tws = tw4 + s * 3072;
        for (int t = tid; t < 1024; t += NT) {
            int j = t & (q - 1);
            int base = ((t & ~(q - 1)) << 2) | j;
            float2 a = z[base];
            float2 b = cmulc(z[base + q],     tws[3 * j + 0]);
            float2 c = cmulc(z[base + 2 * q], tws[3 * j + 1]);
            float2 d = cmulc(z[base + 3 * q], tws[3 * j + 2]);
            float2 p0 = make_float2(a.x + c.x, a.y + c.y);
            float2 p1 = make_float2(a.x - c.x, a.y - c.y);
            float2 p2 = make_float2(b.x + d.x, b.y + d.y);
            float2 p3 = make_float2(b.x - d.x, b.y - d.y);
            z[base]         = make_float2(p0.x + p2.x, p0.y + p2.y);
            z[base + q]     = make_float2(p1.x - p3.y, p1.y + p3.x);
            z[base + 2 * q] = make_float2(p0.x - p2.x, p0.y - p2.y);
            z[base + 3 * q] = make_float2(p1.x + p3.y, p1.y - p3.x);
        }
        __syncthreads();
    }
}

// ---------------------------------------------------------------------------
// Merged prep (1024 threads, per (b,h)): build damped-cosine kernel, fwd 8192
// FFT, apply gate in BR order, inv FFT, fold to 4096, radix-4 fwd -> GBR.
// ---------------------------------------------------------------------------
__global__ __launch_bounds__(1024) void kern_prep(const float* __restrict__ freq,
                                                  const float* __restrict__ damp,
                                                  const float* __restrict__ phase,
                                                  const float* __restrict__ ctrl,
                                                  const float2* __restrict__ twid,
                                                  const float2* __restrict__ tw4,
                                                  float* __restrict__ GBR) {
    __shared__ float sm[2 * PAD_];    // 64 KB
    float* xr = sm;
    float* xi = sm + PAD_;
    const int bh = blockIdx.x, tid = threadIdx.x;
    const int b = bh >> 4, h = bh & 15;

    // build kernel in time domain
    const float fr = freq[h], ed = expf(damp[h]), ph = phase[h];
    for (int f = tid; f < PAD_; f += 1024) {
        float v = 0.f;
        if (f < F_) {
            float t = (float)f / (float)F_;
            v = expf(-ed * t) * cosf(fr * t + ph);
        }
        xr[f] = v; xi[f] = 0.f;
    }
    __syncthreads();
    fft_fwd_dif_t<1024>(xr, xi, tid, 13, twid);   // natural -> BR spectrum

    // gate in BR order
    const float* cp = ctrl + b * (H_ * NC_) + h * NC_;
    for (int j = tid; j < PAD_; j += 1024) {
        int k = (int)(__brev((unsigned)j) >> 19);
        int kk = min(k, PAD_ - k);
        float ip = (float)kk * ((float)(NC_ - 1) / (float)(FB_ - 1));
        int il = min((int)ip, NC_ - 2);
        float iw = ip - (float)il;
        float m = 1.f + cp[il] * (1.f - iw) + cp[il + 1] * iw;
        xr[j] *= m;
        xi[j] *= m;
    }
    __syncthreads();
    fft_inv_dit_t<1024>(xr, xi, tid, 13, twid);   // BR -> natural keff (unscaled)

    // fold to 4096 real kernel, staged through registers
    float g[4];
    const float sc = 1.f / (float)PAD_;
#pragma unroll
    for (int u = 0; u < 4; ++u) {
        int j = tid + u * 1024;
        g[u] = ((j < 2048) ? xr[j] : xr[j + 4096]) * sc;
    }
    __syncthreads();
    float2* z = (float2*)sm;
#pragma unroll
    for (int u = 0; u < 4; ++u) {
        int j = tid + u * 1024;
        z[j] = make_float2(g[u], 0.f);
    }
    __syncthreads();
    fft4_fwd<1024>(z, tid, tw4);                  // natural -> digit-reversed
    for (int j = tid; j < 4096; j += 1024) {
        GBR[((size_t)bh * 4096 + j) * 2 + 0] = z[j].x;
        GBR[((size_t)bh * 4096 + j) * 2 + 1] = z[j].y;
    }
}

// Main conv: 4096-pt radix-4 complex FFT, 2 real channels packed per block.
__global__ __launch_bounds__(256) void kern_conv4(float* __restrict__ field,
                                                  const float* __restrict__ GBR,
                                                  const float2* __restrict__ tw4) {
    __shared__ float2 z[4096];
    const int tid = threadIdx.x;
    const int bh = blockIdx.x >> 6, cp = blockIdx.x & 63;
    float* rowx = field + ((size_t)bh * 128 + 2 * cp) * F_;
    float* rowy = rowx + F_;

    for (int f = tid; f < 2048; f += 256) {
        z[f] = make_float2(rowx[f], rowy[f]);
        z[f + 2048] = make_float2(0.f, 0.f);
    }
    __syncthreads();

    fft4_fwd<256>(z, tid, tw4);

    {
        const float2* G = (const float2*)(GBR) + (size_t)bh * 4096;
        for (int j = tid; j < 4096; j += 256)
            z[j] = cmul(z[j], G[j]);
    }
    __syncthreads();

    fft4_inv<256>(z, tid, tw4);

    const float s = 1.f / 4096.f;
    for (int f = tid; f < 2048; f += 256) {
        float2 v = z[f];
        rowx[f] = v.x * s;
        rowy[f] = v.y * s;
    }
}

// combine WITH fused head coupling:
// y[c] = sum_g coup[h,g] * conv[b,g,c,f];  out written as bf16 hi/lo into
// qkvg q-columns. 1024 thr = 16 waves = 16 consecutive tokens of one (b,h).
__global__ __launch_bounds__(1024) void kern_combine(float* __restrict__ qkvg,
                                                     const float* __restrict__ field,
                                                     const float* __restrict__ coupling) {
    __shared__ float cpl[16];
    const int tid = threadIdx.x;
    const int lane = tid & 63, wv = tid >> 6;
    const int n = blockIdx.x * 16 + wv;
    const int h = blockIdx.y, b = blockIdx.z;
    if (tid < 16) cpl[tid] = coupling[h * 16 + tid];
    __syncthreads();
    const int f = min(n, F_ - 2);
    const size_t row = (size_t)(b * N_ + n) * 4096;
    float pq = qkvg[row + D_ + h * 64 + lane];
    float ynum = 0.f, yden = 0.f;
#pragma unroll
    for (int g = 0; g < 16; ++g) {
        const float* cv = field + (size_t)(b * 16 + g) * 128 * F_;
        float cg = cpl[g];
        ynum += cg * cv[(size_t)lane * F_ + f];
        yden += cg * cv[(size_t)(64 + lane) * F_ + f];
    }
    float gv = qkvg[row + 3 * D_ + h * 64 + lane];
    float s = pq * yden;
    for (int m = 1; m < 64; m <<= 1) s += __shfl_xor(s, m);
    float den = fabsf(s) + 1e-4f;
    float o = pq * ynum / den * (1.f / (1.f + expf(-gv)));
    ushort_t oh, ol;
    split_bf16(o, oh, ol);
    ushort_t* rp = (ushort_t*)(qkvg + row);
    rp[h * 64 + lane] = oh;
    rp[1024 + h * 64 + lane] = ol;
}

// ---------------------------------------------------------------------------
extern "C" void kernel_launch(void* const* d_in, const int* in_sizes, int n_in,
                              void* d_out, int out_size, void* d_ws, size_t ws_size,
                              hipStream_t stream) {
    const float* x      = (const float*)d_in[0];
    const float* w_qkvg = (const float*)d_in[1];
    const float* b_qkvg = (const float*)d_in[2];
    const float* w_out  = (const float*)d_in[3];
    const float* b_out  = (const float*)d_in[4];
    const float* qfm_w  = (const float*)d_in[5];
    const float* qfm_b  = (const float*)d_in[6];
    const float* kfm_w  = (const float*)d_in[7];
    const float* kfm_b  = (const float*)d_in[8];
    const float* wg_w   = (const float*)d_in[9];
    const float* wg_b   = (const float*)d_in[10];
    const float* ln_g   = (const float*)d_in[11];
    const float* ln_b   = (const float*)d_in[12];
    const float* sg_w1  = (const float*)d_in[13];
    const float* sg_b1  = (const float*)d_in[14];
    const float* sg_w2  = (const float*)d_in[15];
    const float* sg_b2  = (const float*)d_in[16];
    const float* wfreq  = (const float*)d_in[17];
    const float* wdamp  = (const float*)d_in[18];
    const float* wphase = (const float*)d_in[19];
    const float* coup   = (const float*)d_in[20];

    float* ws = (float*)d_ws;
    // workspace (floats):
    float*  qkvg   = ws;                 // 33,554,432
    float*  field  = ws + 33554432;      // 16,777,216
    float*  GBR    = ws + 50593792;      //    524,288
    float2* twid   = (float2*)(ws + 51118080);   // 106,496 floats (radix-2)
    float*  q0n    = ws + 51224576;      //      4,096
    float*  h1     = ws + 51228672;      //      4,096
    float*  ctrl   = ws + 51232768;      //      2,048
    ushort_t* wouth = (ushort_t*)(ws + 51234816); // 524,288 floats
    ushort_t* woutl = (ushort_t*)(ws + 51759104); // 524,288 floats
    float2* tw4    = (float2*)(ws + 52283392);    // 36,864 floats (radix-4)
    // end: 52,320,256 floats = 209.3 MB

    // bf16 staging aliases inside `field` (consumed by gemm#1 before feat writes)
    ushort_t* xh  = (ushort_t*)(field);
    ushort_t* xl  = (ushort_t*)(field + 4194304);
    ushort_t* wqh = (ushort_t*)(field + 8388608);
    ushort_t* wql = (ushort_t*)(field + 10485760);

    // 0. twiddles (merged) + splits (merged)
    kern_twid<<<(13 * 4096 + 6 * 3072) / 256, 256, 0, stream>>>(twid, tw4);
    kern_split3<<<(B_ * N_ * D_ + 4 * D_ * D_ + D_ * D_) / 256, 256, 0, stream>>>(
        x, xh, xl, B_ * N_ * D_,
        w_qkvg, wqh, wql, 4 * D_ * D_,
        w_out, wouth, woutl, D_ * D_);

    // 1. qkvg = x @ w_qkvg^T + b_qkvg   (split-bf16 MFMA)
    gemm_mfma<<<dim3(4096 / 128, 8192 / 128), 256, 0, stream>>>(
        xh, xl, D_, wqh, wql, D_, b_qkvg, qkvg, 4 * D_, D_);

    // 2. control path
    kern_ln<<<B_ * H_, 64, 0, stream>>>(qkvg, ln_g, ln_b, q0n);
    gemm_nt<<<dim3(1024 / 64, 1), 256, 0, stream>>>(q0n, sg_w1, sg_b1, h1, B_, D_, D_, D_, 1);
    gemm_nt<<<dim3(512 / 64, 1), 256, 0, stream>>>(h1, sg_w2, sg_b2, ctrl, B_, H_ * NC_, D_, D_, 0);

    // 3. spectra prep (merged base FFT + gate + fold, 1024 thr)
    kern_prep<<<B_ * H_, 1024, 0, stream>>>(wfreq, wdamp, wphase, ctrl, twid, tw4, GBR);

    // 4. featmaps + wg + field build
    kern_feat<<<dim3(N_ / 64, H_, B_), 256, 0, stream>>>(
        qkvg, qfm_w, qfm_b, kfm_w, kfm_b, wg_w, wg_b, field);

    // 5. FFT convolution (radix-4, in place on field)
    kern_conv4<<<B_ * H_ * 64, 256, 0, stream>>>(field, GBR, tw4);

    // 6. combine (+fused coupling) -> att (bf16 hi/lo) into qkvg q-columns
    kern_combine<<<dim3(N_ / 16, H_, B_), 1024, 0, stream>>>(qkvg, field, coup);

    // 7. out = att @ w_out^T + b_out
    gemm_mfma<<<dim3(1024 / 128, 8192 / 128), 256, 0, stream>>>(
        (ushort_t*)qkvg, (ushort_t*)qkvg + 1024, 8192,
        wouth, woutl, D_, b_out, (float*)d_out, D_, D_);
}

// Round 8
// 931.528 us; speedup vs baseline: 1.9778x; 1.9778x over previous
//
#include <hip/hip_runtime.h>
#include <math.h>

// Problem constants
#define B_   4
#define N_   2048
#define D_   1024
#define H_   16
#define d_   64
#define F_   2048
#define PAD_ 8192
#define FB_  4097
#define NC_  32
#define EPS_ 1e-6f
#define PI_F 3.14159265358979323846f
#define PI_D 3.14159265358979323846

typedef unsigned short ushort_t;
typedef short bf16x8 __attribute__((ext_vector_type(8)));
typedef float f32x4  __attribute__((ext_vector_type(4)));

#define GLD16(gp, lp) __builtin_amdgcn_global_load_lds( \
    (const __attribute__((address_space(1))) unsigned int*)(const void*)(gp), \
    (__attribute__((address_space(3))) unsigned int*)(void*)(lp), 16, 0, 0)

// round-to-nearest-even fp32 -> bf16 (bits), plus residual split
__device__ __forceinline__ ushort_t bf16_rne(float v) {
    unsigned b = __float_as_uint(v);
    unsigned rb = b + 0x7fffu + ((b >> 16) & 1u);
    return (ushort_t)(rb >> 16);
}
__device__ __forceinline__ void split_bf16(float v, ushort_t& h, ushort_t& l) {
    h = bf16_rne(v);
    float fh = __uint_as_float((unsigned)h << 16);
    l = bf16_rne(v - fh);
}

__device__ __forceinline__ float2 cmul(float2 a, float2 w) {
    return make_float2(a.x * w.x - a.y * w.y, a.x * w.y + a.y * w.x);
}
__device__ __forceinline__ float2 cmulc(float2 a, float2 w) {   // a * conj(w)
    return make_float2(a.x * w.x + a.y * w.y, a.y * w.x - a.x * w.y);
}

// ---------------------------------------------------------------------------
// Merged twiddle builder: radix-2 table (13*4096) then radix-4 table (6*3072)
// ---------------------------------------------------------------------------
__global__ __launch_bounds__(256) void kern_twid(float2* __restrict__ twid,
                                                 float2* __restrict__ tw4) {
    int idx = blockIdx.x * 256 + threadIdx.x;
    if (idx < 13 * 4096) {
        const int lh = idx >> 12, t = idx & 4095;
        const int hh = 1 << lh;
        const int j = t & (hh - 1);
        double s, c;
        sincos(-PI_D * (double)j / (double)hh, &s, &c);
        twid[idx] = make_float2((float)c, (float)s);
    } else {
        idx -= 13 * 4096;
        if (idx < 6 * 3072) {
            const int s = idx / 3072;
            const int r = idx - s * 3072;
            const int j = r / 3;
            const int m = r - 3 * j + 1;
            const int q = 1024 >> (2 * s);
            double sn, cs;
            sincos(-2.0 * PI_D * (double)(m * (j & (q - 1))) / (double)(4 * q), &sn, &cs);
            tw4[idx] = make_float2((float)cs, (float)sn);
        }
    }
}

// ---------------------------------------------------------------------------
// Merged split: three fp32 arrays -> (hi, lo) bf16 arrays in one launch
// ---------------------------------------------------------------------------
__global__ __launch_bounds__(256) void kern_split3(
        const float* __restrict__ s0, ushort_t* __restrict__ h0, ushort_t* __restrict__ l0, int n0,
        const float* __restrict__ s1, ushort_t* __restrict__ h1, ushort_t* __restrict__ l1, int n1,
        const float* __restrict__ s2, ushort_t* __restrict__ h2, ushort_t* __restrict__ l2, int n2) {
    int i = blockIdx.x * 256 + threadIdx.x;
    const float* s; ushort_t* hh; ushort_t* ll; int k;
    if (i < n0)                { s = s0; hh = h0; ll = l0; k = i; }
    else if (i < n0 + n1)      { s = s1; hh = h1; ll = l1; k = i - n0; }
    else if (i < n0 + n1 + n2) { s = s2; hh = h2; ll = l2; k = i - n0 - n1; }
    else return;
    ushort_t h, l;
    split_bf16(s[k], h, l);
    hh[k] = h; ll[k] = l;
}

// ---------------------------------------------------------------------------
// Split-bf16 MFMA NT GEMM: C = A*B^T + bias. 3 cross-products.
// 128x128 tile, BK=32, 256 thr. M, Nn, K multiples of 128.
// ---------------------------------------------------------------------------
__global__ __launch_bounds__(256) void gemm_mfma(
        const ushort_t* __restrict__ Ah, const ushort_t* __restrict__ Al, int lda,
        const ushort_t* __restrict__ Bh, const ushort_t* __restrict__ Bl, int ldb,
        const float* __restrict__ bias, float* __restrict__ C,
        int Nn, int K) {
    __shared__ __align__(16) ushort_t At0[128 * 32];
    __shared__ __align__(16) ushort_t At1[128 * 32];
    __shared__ __align__(16) ushort_t Bt0[128 * 32];
    __shared__ __align__(16) ushort_t Bt1[128 * 32];

    const int tid = threadIdx.x;
    const int wv = tid >> 6, lane = tid & 63;
    const int quad = lane >> 4, lrow = lane & 15;
    const int m0 = blockIdx.y * 128, n0 = blockIdx.x * 128;
    const int mw = (wv >> 1) * 64, nw = (wv & 1) * 64;

    const int srow = lane >> 2;
    const int schunk = (lane & 3) * 8;

    f32x4 acc[4][4] = {};

    for (int k0 = 0; k0 < K; k0 += 32) {
        {
            const size_t ga = (size_t)(m0 + wv * 32 + srow) * lda + k0 + schunk;
            const size_t gb = (size_t)(n0 + wv * 32 + srow) * ldb + k0 + schunk;
            const size_t ga2 = ga + (size_t)16 * lda;
            const size_t gb2 = gb + (size_t)16 * ldb;
            GLD16(Ah + ga,  &At0[(wv * 32) * 32]);
            GLD16(Ah + ga2, &At0[(wv * 32 + 16) * 32]);
            GLD16(Al + ga,  &At1[(wv * 32) * 32]);
            GLD16(Al + ga2, &At1[(wv * 32 + 16) * 32]);
            GLD16(Bh + gb,  &Bt0[(wv * 32) * 32]);
            GLD16(Bh + gb2, &Bt0[(wv * 32 + 16) * 32]);
            GLD16(Bl + gb,  &Bt1[(wv * 32) * 32]);
            GLD16(Bl + gb2, &Bt1[(wv * 32 + 16) * 32]);
        }
        __syncthreads();

        bf16x8 a0[4], a1[4], b0[4], b1[4];
#pragma unroll
        for (int i = 0; i < 4; ++i) {
            a0[i] = *(const bf16x8*)&At0[(mw + i * 16 + lrow) * 32 + quad * 8];
            a1[i] = *(const bf16x8*)&At1[(mw + i * 16 + lrow) * 32 + quad * 8];
            b0[i] = *(const bf16x8*)&Bt0[(nw + i * 16 + lrow) * 32 + quad * 8];
            b1[i] = *(const bf16x8*)&Bt1[(nw + i * 16 + lrow) * 32 + quad * 8];
        }
#pragma unroll
        for (int mi = 0; mi < 4; ++mi)
#pragma unroll
            for (int nj = 0; nj < 4; ++nj) {
                acc[mi][nj] = __builtin_amdgcn_mfma_f32_16x16x32_bf16(a0[mi], b0[nj], acc[mi][nj], 0, 0, 0);
                acc[mi][nj] = __builtin_amdgcn_mfma_f32_16x16x32_bf16(a0[mi], b1[nj], acc[mi][nj], 0, 0, 0);
                acc[mi][nj] = __builtin_amdgcn_mfma_f32_16x16x32_bf16(a1[mi], b0[nj], acc[mi][nj], 0, 0, 0);
            }
        __syncthreads();
    }

#pragma unroll
    for (int mi = 0; mi < 4; ++mi) {
        const int row = m0 + mw + mi * 16 + quad * 4;
#pragma unroll
        for (int nj = 0; nj < 4; ++nj) {
            const int col = n0 + nw + nj * 16 + lrow;
            const float bv = bias[col];
#pragma unroll
            for (int r = 0; r < 4; ++r)
                C[(size_t)(row + r) * Nn + col] = acc[mi][nj][r] + bv;
        }
    }
}

// ---------------------------------------------------------------------------
// Generic fp32 NT GEMM (only the tiny M=4 control GEMMs).
// ---------------------------------------------------------------------------
__device__ __forceinline__ float gelu_f(float x) {
    return 0.5f * x * (1.f + tanhf(0.7978845608028654f * (x + 0.044715f * x * x * x)));
}

__global__ __launch_bounds__(256) void gemm_nt(const float* __restrict__ A,
                                               const float* __restrict__ Bm,
                                               const float* __restrict__ bias,
                                               float* __restrict__ C,
                                               int M, int Nn, int K, int lda, int act) {
    __shared__ float As[16][64];
    __shared__ float Bs[16][64];
    const int tid = threadIdx.x;
    const int tx = tid & 15, ty = tid >> 4;
    const int m0 = blockIdx.y * 64, n0 = blockIdx.x * 64;

    float acc[4][4];
#pragma unroll
    for (int i = 0; i < 4; ++i)
#pragma unroll
        for (int j = 0; j < 4; ++j) acc[i][j] = 0.f;

    const int lr = tid >> 2;
    const int lk = (tid & 3) * 4;

    for (int k0 = 0; k0 < K; k0 += 16) {
        float4 av = make_float4(0.f, 0.f, 0.f, 0.f);
        float4 bv = make_float4(0.f, 0.f, 0.f, 0.f);
        if (m0 + lr < M)
            av = *(const float4*)(A + (size_t)(m0 + lr) * lda + k0 + lk);
        if (n0 + lr < Nn)
            bv = *(const float4*)(Bm + (size_t)(n0 + lr) * K + k0 + lk);
        As[lk + 0][lr] = av.x; As[lk + 1][lr] = av.y;
        As[lk + 2][lr] = av.z; As[lk + 3][lr] = av.w;
        Bs[lk + 0][lr] = bv.x; Bs[lk + 1][lr] = bv.y;
        Bs[lk + 2][lr] = bv.z; Bs[lk + 3][lr] = bv.w;
        __syncthreads();
#pragma unroll
        for (int k = 0; k < 16; ++k) {
            float a[4], b[4];
#pragma unroll
            for (int i = 0; i < 4; ++i) a[i] = As[k][ty * 4 + i];
#pragma unroll
            for (int j = 0; j < 4; ++j) b[j] = Bs[k][tx * 4 + j];
#pragma unroll
            for (int i = 0; i < 4; ++i)
#pragma unroll
                for (int j = 0; j < 4; ++j) acc[i][j] += a[i] * b[j];
        }
        __syncthreads();
    }
#pragma unroll
    for (int i = 0; i < 4; ++i) {
        int row = m0 + ty * 4 + i;
        if (row >= M) continue;
#pragma unroll
        for (int j = 0; j < 4; ++j) {
            int col = n0 + tx * 4 + j;
            if (col >= Nn) continue;
            float v = acc[i][j] + bias[col];
            if (act == 1) v = gelu_f(v);
            C[(size_t)row * Nn + col] = v;
        }
    }
}

// ---------------------------------------------------------------------------
// Featuremap + field build. Tiles padded to [68] (16B-aligned rows) for
// float4 broadcast LDS reads; wbuf stays [65] (transposed store pattern).
// ---------------------------------------------------------------------------
__global__ __launch_bounds__(256) void kern_feat(float* __restrict__ qkvg,
                                                 const float* __restrict__ qfm_w,
                                                 const float* __restrict__ qfm_b,
                                                 const float* __restrict__ kfm_w,
                                                 const float* __restrict__ kfm_b,
                                                 const float* __restrict__ wg_w,
                                                 const float* __restrict__ wg_b,
                                                 float* __restrict__ field) {
    __shared__ __align__(16) float in_t[64][68];
    __shared__ __align__(16) float tmp[64][68];
    __shared__ float wbuf[64][65];
    __shared__ float bsm[64];
    __shared__ float wsm[64];
    __shared__ float wgbuf[64];

    const int tid = threadIdx.x;
    const int lane = tid & 63, grp = tid >> 6;
    const int n0 = blockIdx.x * 64;
    const int h = blockIdx.y, b = blockIdx.z;
    const size_t rowbase = (size_t)(b * N_ + n0) * 4096;

    const int lr4 = tid >> 4;          // 0..15 row within 16-row group
    const int lc4 = (tid & 15) * 4;    // 0,4,...,60 col

#define LOAD64x64(dst, off) \
    for (int it = 0; it < 4; ++it) { \
        int r = lr4 + it * 16; \
        float4 v = *(const float4*)&qkvg[rowbase + (size_t)r * 4096 + (off) + lc4]; \
        *(float4*)&dst[r][lc4] = v; \
    }

#define MLP_LAYER(dstarr, srcarr) { \
    const int j = lane, ibase = grp * 16; \
    float acc[16]; \
    _Pragma("unroll") for (int ii = 0; ii < 16; ++ii) acc[ii] = 0.f; \
    for (int c4 = 0; c4 < 64; c4 += 4) { \
        float w0 = wbuf[c4 + 0][j], w1 = wbuf[c4 + 1][j]; \
        float w2 = wbuf[c4 + 2][j], w3 = wbuf[c4 + 3][j]; \
        _Pragma("unroll") for (int ii = 0; ii < 16; ++ii) { \
            float4 iv = *(const float4*)&srcarr[ibase + ii][c4]; \
            acc[ii] += iv.x * w0 + iv.y * w1 + iv.z * w2 + iv.w * w3; \
        } \
    } \
    float bj = bsm[j]; \
    _Pragma("unroll") for (int ii = 0; ii < 16; ++ii) \
        dstarr[ibase + ii][j] = fmaxf(acc[ii] + bj, 0.f); \
    }

    // ============ K path ============
    LOAD64x64(in_t, D_ + h * 64)
    for (int it = 0; it < 16; ++it) {
        int r = grp + 4 * it;
        wbuf[lane][r] = kfm_w[(size_t)r * 64 + lane];   // wbuf[c][j] = W0[j][c]
    }
    if (tid < 64) { bsm[tid] = kfm_b[tid]; wsm[tid] = wg_w[tid]; }
    __syncthreads();
    if (tid < 64) {   // wg from raw k
        float s = 0.f;
        for (int c4 = 0; c4 < 64; c4 += 4) {
            float4 iv = *(const float4*)&in_t[tid][c4];
            s += iv.x * wsm[c4] + iv.y * wsm[c4 + 1] + iv.z * wsm[c4 + 2] + iv.w * wsm[c4 + 3];
        }
        s += wg_b[0];
        wgbuf[tid] = 1.f / (1.f + expf(-s));
    }
    MLP_LAYER(tmp, in_t)
    __syncthreads();
    for (int it = 0; it < 16; ++it) {
        int r = grp + 4 * it;
        wbuf[lane][r] = kfm_w[(size_t)(64 + r) * 64 + lane];
    }
    if (tid < 64) bsm[tid] = kfm_b[64 + tid];
    __syncthreads();
    {   // L2: phi_k -> in_t (+EPS)
        const int j = lane, ibase = grp * 16;
        float acc[16];
#pragma unroll
        for (int ii = 0; ii < 16; ++ii) acc[ii] = 0.f;
        for (int c4 = 0; c4 < 64; c4 += 4) {
            float w0 = wbuf[c4 + 0][j], w1 = wbuf[c4 + 1][j];
            float w2 = wbuf[c4 + 2][j], w3 = wbuf[c4 + 3][j];
#pragma unroll
            for (int ii = 0; ii < 16; ++ii) {
                float4 iv = *(const float4*)&tmp[ibase + ii][c4];
                acc[ii] += iv.x * w0 + iv.y * w1 + iv.z * w2 + iv.w * w3;
            }
        }
        float bj = bsm[j];
#pragma unroll
        for (int ii = 0; ii < 16; ++ii)
            in_t[ibase + ii][j] = fmaxf(acc[ii] + bj, 0.f) + EPS_;
    }
    __syncthreads();
    LOAD64x64(tmp, 2 * D_ + h * 64)     // V -> tmp
    __syncthreads();

    // field write: write[c<64] = wg*pk*v ; write[c>=64] = wg*pk
    {
        float* frow = field + (size_t)(b * H_ + h) * 128 * F_;
        const bool last = (n0 == N_ - 64);
        for (int c = grp; c < 128; c += 4) {
            int i = lane;
            float v = (c < 64) ? wgbuf[i] * in_t[i][c] * tmp[i][c]
                               : wgbuf[i] * in_t[i][c - 64];
            if (last) {
                if (i == 62) {
                    float v2 = (c < 64) ? wgbuf[63] * in_t[63][c] * tmp[63][c]
                                        : wgbuf[63] * in_t[63][c - 64];
                    v += v2;
                } else if (i == 63) v = 0.f;
            }
            frow[(size_t)c * F_ + n0 + i] = v;
        }
    }
    __syncthreads();

    // ============ Q path ============
    LOAD64x64(in_t, h * 64)
    for (int it = 0; it < 16; ++it) {
        int r = grp + 4 * it;
        wbuf[lane][r] = qfm_w[(size_t)r * 64 + lane];
    }
    if (tid < 64) bsm[tid] = qfm_b[tid];
    __syncthreads();
    MLP_LAYER(tmp, in_t)
    __syncthreads();
    for (int it = 0; it < 16; ++it) {
        int r = grp + 4 * it;
        wbuf[lane][r] = qfm_w[(size_t)(64 + r) * 64 + lane];
    }
    if (tid < 64) bsm[tid] = qfm_b[64 + tid];
    __syncthreads();
    {   // L2: phi_q -> qkvg k-columns
        const int j = lane, ibase = grp * 16;
        float acc[16];
#pragma unroll
        for (int ii = 0; ii < 16; ++ii) acc[ii] = 0.f;
        for (int c4 = 0; c4 < 64; c4 += 4) {
            float w0 = wbuf[c4 + 0][j], w1 = wbuf[c4 + 1][j];
            float w2 = wbuf[c4 + 2][j], w3 = wbuf[c4 + 3][j];
#pragma unroll
            for (int ii = 0; ii < 16; ++ii) {
                float4 iv = *(const float4*)&tmp[ibase + ii][c4];
                acc[ii] += iv.x * w0 + iv.y * w1 + iv.z * w2 + iv.w * w3;
            }
        }
        float bj = bsm[j];
#pragma unroll
        for (int ii = 0; ii < 16; ++ii) {
            float v = fmaxf(acc[ii] + bj, 0.f) + EPS_;
            qkvg[rowbase + (size_t)(ibase + ii) * 4096 + D_ + h * 64 + j] = v;
        }
    }
#undef LOAD64x64
#undef MLP_LAYER
}

// ---------------------------------------------------------------------------
// LayerNorm of q token 0 -> q0n (B x 1024).
// ---------------------------------------------------------------------------
__global__ void kern_ln(const float* __restrict__ qkvg,
                        const float* __restrict__ ln_g,
                        const float* __restrict__ ln_b,
                        float* __restrict__ q0n) {
    const int bh = blockIdx.x, c = threadIdx.x;
    const int b = bh >> 4, h = bh & 15;
    float x = qkvg[(size_t)(b * N_) * 4096 + h * 64 + c];
    float mu = x;
    for (int m = 1; m < 64; m <<= 1) mu += __shfl_xor(mu, m);
    mu *= (1.f / 64.f);
    float dv = (x - mu) * (x - mu);
    for (int m = 1; m < 64; m <<= 1) dv += __shfl_xor(dv, m);
    float var = dv * (1.f / 64.f);
    q0n[b * 1024 + h * 64 + c] = (x - mu) * rsqrtf(var + 1e-5f) * ln_g[c] + ln_b[c];
}

// ---------------------------------------------------------------------------
// Templated table-driven FFT helpers (NT = threads per block).
// ---------------------------------------------------------------------------
template <int NT>
__device__ __forceinline__ void fft_fwd_dif_t(float* xr, float* xi, int tid, int logn,
                                              const float2* __restrict__ twid) {
    const int nb = 1 << (logn - 1);
    for (int lh = logn - 1; lh >= 0; --lh) {
        const int hh = 1 << lh;
        const float2* tws = twid + lh * 4096;
        for (int t = tid; t < nb; t += NT) {
            int j = t & (hh - 1);
            int i1 = ((t >> lh) << (lh + 1)) | j;
            int i2 = i1 + hh;
            float2 tw = tws[t];
            float ar = xr[i1], ai = xi[i1];
            float br = xr[i2], bi = xi[i2];
            xr[i1] = ar + br; xi[i1] = ai + bi;
            float tr = ar - br, ti = ai - bi;
            xr[i2] = tr * tw.x - ti * tw.y;
            xi[i2] = tr * tw.y + ti * tw.x;
        }
        __syncthreads();
    }
}

template <int NT>
__device__ __forceinline__ void fft_inv_dit_t(float* xr, float* xi, int tid, int logn,
                                              const float2* __restrict__ twid) {
    const int nb = 1 << (logn - 1);
    for (int lh = 0; lh < logn; ++lh) {
        const int hh = 1 << lh;
        const float2* tws = twid + lh * 4096;
        for (int t = tid; t < nb; t += NT) {
            int j = t & (hh - 1);
            int i1 = ((t >> lh) << (lh + 1)) | j;
            int i2 = i1 + hh;
            float2 tw = tws[t];   // conj applied
            float br = xr[i2], bi = xi[i2];
            float tr = br * tw.x + bi * tw.y;
            float ti = bi * tw.x - br * tw.y;
            float ar = xr[i1], ai = xi[i1];
            xr[i1] = ar + tr; xi[i1] = ai + ti;
            xr[i2] = ar - tr; xi[i2] = ai - ti;
        }
        __syncthreads();
    }
}

template <int NT>
__device__ __forceinline__ void fft4_fwd(float2* z, int tid,
                                         const float2* __restrict__ tw4) {
#pragma unroll
    for (int s = 0; s < 6; ++s) {
        const int q = 1024 >> (2 * s);
        const float2* tws = tw4 + s * 3072;
        for (int t = tid; t < 1024; t += NT) {
            int j = t & (q - 1);
            int base = ((t & ~(q - 1)) << 2) | j;
            float2 a = z[base], b = z[base + q], c = z[base + 2 * q], d = z[base + 3 * q];
            float2 s0 = make_float2(a.x + c.x, a.y + c.y);
            float2 s1 = make_float2(a.x - c.x, a.y - c.y);
            float2 s2 = make_float2(b.x + d.x, b.y + d.y);
            float2 s3 = make_float2(b.x - d.x, b.y - d.y);
            float2 m1 = make_float2(s1.x + s3.y, s1.y - s3.x);
            float2 m2 = make_float2(s0.x - s2.x, s0.y - s2.y);
            float2 m3 = make_float2(s1.x - s3.y, s1.y + s3.x);
            z[base]         = make_float2(s0.x + s2.x, s0.y + s2.y);
            z[base + q]     = cmul(m1, tws[3 * j + 0]);
            z[base + 2 * q] = cmul(m2, tws[3 * j + 1]);
            z[base + 3 * q] = cmul(m3, tws[3 * j + 2]);
        }
        __syncthreads();
    }
}

template <int NT>
__device__ __forceinline__ void fft4_inv(float2* z, int tid,
                                         const float2* __restrict__ tw4) {
#pragma unroll
    for (int s = 5; s >= 0; --s) {
        const int q = 1024 >> (2 * s);
        const float2* tws = tw4 + s * 3072;
        for (int t = tid; t < 1024; t += NT) {
            int j = t & (q - 1);
            int base = ((t & ~(q - 1)) << 2) | j;
            float2 a = z[base];
            float2 b = cmulc(z[base + q],     tws[3 * j + 0]);
            float2 c = cmulc(z[base + 2 * q], tws[3 * j + 1]);
            float2 d = cmulc(z[base + 3 * q], tws[3 * j + 2]);
            float2 p0 = make_float2(a.x + c.x, a.y + c.y);
            float2 p1 = make_float2(a.x - c.x, a.y - c.y);
            float2 p2 = make_float2(b.x + d.x, b.y + d.y);
            float2 p3 = make_float2(b.x - d.x, b.y - d.y);
            z[base]         = make_float2(p0.x + p2.x, p0.y + p2.y);
            z[base + q]     = make_float2(p1.x - p3.y, p1.y + p3.x);
            z[base + 2 * q] = make_float2(p0.x - p2.x, p0.y - p2.y);
            z[base + 3 * q] = make_float2(p1.x + p3.y, p1.y - p3.x);
        }
        __syncthreads();
    }
}

// ---------------------------------------------------------------------------
// Merged prep (1024 threads, per (b,h)): build damped-cosine kernel, fwd 8192
// FFT, apply gate in BR order, inv FFT, fold to 4096, radix-4 fwd -> GBR.
// ---------------------------------------------------------------------------
__global__ __launch_bounds__(1024) void kern_prep(const float* __restrict__ freq,
                                                  const float* __restrict__ damp,
                                                  const float* __restrict__ phase,
                                                  const float* __restrict__ ctrl,
                                                  const float2* __restrict__ twid,
                                                  const float2* __restrict__ tw4,
                                                  float* __restrict__ GBR) {
    __shared__ float sm[2 * PAD_];    // 64 KB
    float* xr = sm;
    float* xi = sm + PAD_;
    const int bh = blockIdx.x, tid = threadIdx.x;
    const int b = bh >> 4, h = bh & 15;

    // build kernel in time domain
    const float fr = freq[h], ed = expf(damp[h]), ph = phase[h];
    for (int f = tid; f < PAD_; f += 1024) {
        float v = 0.f;
        if (f < F_) {
            float t = (float)f / (float)F_;
            v = expf(-ed * t) * cosf(fr * t + ph);
        }
        xr[f] = v; xi[f] = 0.f;
    }
    __syncthreads();
    fft_fwd_dif_t<1024>(xr, xi, tid, 13, twid);   // natural -> BR spectrum

    // gate in BR order
    const float* cp = ctrl + b * (H_ * NC_) + h * NC_;
    for (int j = tid; j < PAD_; j += 1024) {
        int k = (int)(__brev((unsigned)j) >> 19);
        int kk = min(k, PAD_ - k);
        float ip = (float)kk * ((float)(NC_ - 1) / (float)(FB_ - 1));
        int il = min((int)ip, NC_ - 2);
        float iw = ip - (float)il;
        float m = 1.f + cp[il] * (1.f - iw) + cp[il + 1] * iw;
        xr[j] *= m;
        xi[j] *= m;
    }
    __syncthreads();
    fft_inv_dit_t<1024>(xr, xi, tid, 13, twid);   // BR -> natural keff (unscaled)

    // fold to 4096 real kernel, staged through registers
    float g[4];
    const float sc = 1.f / (float)PAD_;
#pragma unroll
    for (int u = 0; u < 4; ++u) {
        int j = tid + u * 1024;
        g[u] = ((j < 2048) ? xr[j] : xr[j + 4096]) * sc;
    }
    __syncthreads();
    float2* z = (float2*)sm;
#pragma unroll
    for (int u = 0; u < 4; ++u) {
        int j = tid + u * 1024;
        z[j] = make_float2(g[u], 0.f);
    }
    __syncthreads();
    fft4_fwd<1024>(z, tid, tw4);                  // natural -> digit-reversed
    for (int j = tid; j < 4096; j += 1024) {
        GBR[((size_t)bh * 4096 + j) * 2 + 0] = z[j].x;
        GBR[((size_t)bh * 4096 + j) * 2 + 1] = z[j].y;
    }
}

// Main conv: 4096-pt radix-4 complex FFT, 2 real channels packed per block.
__global__ __launch_bounds__(256) void kern_conv4(float* __restrict__ field,
                                                  const float* __restrict__ GBR,
                                                  const float2* __restrict__ tw4) {
    __shared__ float2 z[4096];
    const int tid = threadIdx.x;
    const int bh = blockIdx.x >> 6, cp = blockIdx.x & 63;
    float* rowx = field + ((size_t)bh * 128 + 2 * cp) * F_;
    float* rowy = rowx + F_;

    for (int f = tid; f < 2048; f += 256) {
        z[f] = make_float2(rowx[f], rowy[f]);
        z[f + 2048] = make_float2(0.f, 0.f);
    }
    __syncthreads();

    fft4_fwd<256>(z, tid, tw4);

    {
        const float2* G = (const float2*)(GBR) + (size_t)bh * 4096;
        for (int j = tid; j < 4096; j += 256)
            z[j] = cmul(z[j], G[j]);
    }
    __syncthreads();

    fft4_inv<256>(z, tid, tw4);

    const float s = 1.f / 4096.f;
    for (int f = tid; f < 2048; f += 256) {
        float2 v = z[f];
        rowx[f] = v.x * s;
        rowy[f] = v.y * s;
    }
}

// head coupling IN PLACE: field[b,h,c,f] = sum_g coup[h,g]*field_old[b,g,c,f]
// One block owns (b, all heads, c, f-chunk) -> safe in place, fully coalesced.
__global__ __launch_bounds__(256) void kern_coupling(float* __restrict__ field,
                                                     const float* __restrict__ coupling) {
    __shared__ float cp[16][16];
    const int tid = threadIdx.x;
    cp[tid >> 4][tid & 15] = coupling[tid];
    __syncthreads();
    const int f = blockIdx.x * 256 + tid;
    const int c = blockIdx.y;
    const int b = blockIdx.z;
    float val[16];
#pragma unroll
    for (int g = 0; g < 16; ++g)
        val[g] = field[((size_t)(b * 16 + g) * 128 + c) * F_ + f];
    float out[16];
#pragma unroll
    for (int hh = 0; hh < 16; ++hh) {
        float s = 0.f;
#pragma unroll
        for (int g = 0; g < 16; ++g) s += cp[hh][g] * val[g];
        out[hh] = s;
    }
#pragma unroll
    for (int hh = 0; hh < 16; ++hh)
        field[((size_t)(b * 16 + hh) * 128 + c) * F_ + f] = out[hh];
}

// combine -> att written as bf16 hi/lo into qkvg q-columns.
// 1024 thr = 16 waves = 16 consecutive tokens of one (b,h); 64B field lines
// are fully consumed across the block's 16 tokens.
__global__ __launch_bounds__(1024) void kern_combine(float* __restrict__ qkvg,
                                                     const float* __restrict__ field) {
    const int tid = threadIdx.x;
    const int lane = tid & 63, wv = tid >> 6;
    const int n = blockIdx.x * 16 + wv;
    const int h = blockIdx.y, b = blockIdx.z;
    const int f = min(n, F_ - 2);
    const size_t row = (size_t)(b * N_ + n) * 4096;
    float pq = qkvg[row + D_ + h * 64 + lane];
    const float* cv = field + (size_t)(b * H_ + h) * 128 * F_;
    float ynum = cv[(size_t)lane * F_ + f];
    float yden = cv[(size_t)(64 + lane) * F_ + f];
    float gv = qkvg[row + 3 * D_ + h * 64 + lane];
    float s = pq * yden;
    for (int m = 1; m < 64; m <<= 1) s += __shfl_xor(s, m);
    float den = fabsf(s) + 1e-4f;
    float o = pq * ynum / den * (1.f / (1.f + expf(-gv)));
    ushort_t oh, ol;
    split_bf16(o, oh, ol);
    ushort_t* rp = (ushort_t*)(qkvg + row);
    rp[h * 64 + lane] = oh;
    rp[1024 + h * 64 + lane] = ol;
}

// ---------------------------------------------------------------------------
extern "C" void kernel_launch(void* const* d_in, const int* in_sizes, int n_in,
                              void* d_out, int out_size, void* d_ws, size_t ws_size,
                              hipStream_t stream) {
    const float* x      = (const float*)d_in[0];
    const float* w_qkvg = (const float*)d_in[1];
    const float* b_qkvg = (const float*)d_in[2];
    const float* w_out  = (const float*)d_in[3];
    const float* b_out  = (const float*)d_in[4];
    const float* qfm_w  = (const float*)d_in[5];
    const float* qfm_b  = (const float*)d_in[6];
    const float* kfm_w  = (const float*)d_in[7];
    const float* kfm_b  = (const float*)d_in[8];
    const float* wg_w   = (const float*)d_in[9];
    const float* wg_b   = (const float*)d_in[10];
    const float* ln_g   = (const float*)d_in[11];
    const float* ln_b   = (const float*)d_in[12];
    const float* sg_w1  = (const float*)d_in[13];
    const float* sg_b1  = (const float*)d_in[14];
    const float* sg_w2  = (const float*)d_in[15];
    const float* sg_b2  = (const float*)d_in[16];
    const float* wfreq  = (const float*)d_in[17];
    const float* wdamp  = (const float*)d_in[18];
    const float* wphase = (const float*)d_in[19];
    const float* coup   = (const float*)d_in[20];

    float* ws = (float*)d_ws;
    // workspace (floats):
    float*  qkvg   = ws;                 // 33,554,432
    float*  field  = ws + 33554432;      // 16,777,216
    float*  GBR    = ws + 50593792;      //    524,288
    float2* twid   = (float2*)(ws + 51118080);   // 106,496 floats (radix-2)
    float*  q0n    = ws + 51224576;      //      4,096
    float*  h1     = ws + 51228672;      //      4,096
    float*  ctrl   = ws + 51232768;      //      2,048
    ushort_t* wouth = (ushort_t*)(ws + 51234816); // 524,288 floats
    ushort_t* woutl = (ushort_t*)(ws + 51759104); // 524,288 floats
    float2* tw4    = (float2*)(ws + 52283392);    // 36,864 floats (radix-4)
    // end: 52,320,256 floats = 209.3 MB

    // bf16 staging aliases inside `field` (consumed by gemm#1 before feat writes)
    ushort_t* xh  = (ushort_t*)(field);
    ushort_t* xl  = (ushort_t*)(field + 4194304);
    ushort_t* wqh = (ushort_t*)(field + 8388608);
    ushort_t* wql = (ushort_t*)(field + 10485760);

    // 0. twiddles (merged) + splits (merged)
    kern_twid<<<(13 * 4096 + 6 * 3072) / 256, 256, 0, stream>>>(twid, tw4);
    kern_split3<<<(B_ * N_ * D_ + 4 * D_ * D_ + D_ * D_) / 256, 256, 0, stream>>>(
        x, xh, xl, B_ * N_ * D_,
        w_qkvg, wqh, wql, 4 * D_ * D_,
        w_out, wouth, woutl, D_ * D_);

    // 1. qkvg = x @ w_qkvg^T + b_qkvg   (split-bf16 MFMA)
    gemm_mfma<<<dim3(4096 / 128, 8192 / 128), 256, 0, stream>>>(
        xh, xl, D_, wqh, wql, D_, b_qkvg, qkvg, 4 * D_, D_);

    // 2. control path
    kern_ln<<<B_ * H_, 64, 0, stream>>>(qkvg, ln_g, ln_b, q0n);
    gemm_nt<<<dim3(1024 / 64, 1), 256, 0, stream>>>(q0n, sg_w1, sg_b1, h1, B_, D_, D_, D_, 1);
    gemm_nt<<<dim3(512 / 64, 1), 256, 0, stream>>>(h1, sg_w2, sg_b2, ctrl, B_, H_ * NC_, D_, D_, 0);

    // 3. spectra prep (merged base FFT + gate + fold, 1024 thr)
    kern_prep<<<B_ * H_, 1024, 0, stream>>>(wfreq, wdamp, wphase, ctrl, twid, tw4, GBR);

    // 4. featmaps + wg + field build
    kern_feat<<<dim3(N_ / 64, H_, B_), 256, 0, stream>>>(
        qkvg, qfm_w, qfm_b, kfm_w, kfm_b, wg_w, wg_b, field);

    // 5. FFT convolution (radix-4, in place on field)
    kern_conv4<<<B_ * H_ * 64, 256, 0, stream>>>(field, GBR, tw4);

    // 6. head coupling (in place, coalesced)
    kern_coupling<<<dim3(F_ / 256, 128, B_), 256, 0, stream>>>(field, coup);

    // 7. combine -> att (bf16 hi/lo) into qkvg q-columns
    kern_combine<<<dim3(N_ / 16, H_, B_), 1024, 0, stream>>>(qkvg, field);

    // 8. out = att @ w_out^T + b_out
    gemm_mfma<<<dim3(1024 / 128, 8192 / 128), 256, 0, stream>>>(
        (ushort_t*)qkvg, (ushort_t*)qkvg + 1024, 8192,
        wouth, woutl, D_, b_out, (float*)d_out, D_, D_);
}

// Round 9
// 910.557 us; speedup vs baseline: 2.0234x; 1.0230x over previous
//
#include <hip/hip_runtime.h>
#include <math.h>

// Problem constants
#define B_   4
#define N_   2048
#define D_   1024
#define H_   16
#define d_   64
#define F_   2048
#define PAD_ 8192
#define FB_  4097
#define NC_  32
#define EPS_ 1e-6f
#define PI_F 3.14159265358979323846f
#define PI_D 3.14159265358979323846

typedef unsigned short ushort_t;
typedef short bf16x8 __attribute__((ext_vector_type(8)));
typedef float f32x4  __attribute__((ext_vector_type(4)));

#define GLD16(gp, lp) __builtin_amdgcn_global_load_lds( \
    (const __attribute__((address_space(1))) unsigned int*)(const void*)(gp), \
    (__attribute__((address_space(3))) unsigned int*)(void*)(lp), 16, 0, 0)

// round-to-nearest-even fp32 -> bf16 (bits), plus residual split
__device__ __forceinline__ ushort_t bf16_rne(float v) {
    unsigned b = __float_as_uint(v);
    unsigned rb = b + 0x7fffu + ((b >> 16) & 1u);
    return (ushort_t)(rb >> 16);
}
__device__ __forceinline__ void split_bf16(float v, ushort_t& h, ushort_t& l) {
    h = bf16_rne(v);
    float fh = __uint_as_float((unsigned)h << 16);
    l = bf16_rne(v - fh);
}

__device__ __forceinline__ float2 cmul(float2 a, float2 w) {
    return make_float2(a.x * w.x - a.y * w.y, a.x * w.y + a.y * w.x);
}
__device__ __forceinline__ float2 cmulc(float2 a, float2 w) {   // a * conj(w)
    return make_float2(a.x * w.x + a.y * w.y, a.y * w.x - a.x * w.y);
}

// ---------------------------------------------------------------------------
// Merged twiddle builder: radix-2 table (13*4096) then radix-4 table (6*3072)
// ---------------------------------------------------------------------------
__global__ __launch_bounds__(256) void kern_twid(float2* __restrict__ twid,
                                                 float2* __restrict__ tw4) {
    int idx = blockIdx.x * 256 + threadIdx.x;
    if (idx < 13 * 4096) {
        const int lh = idx >> 12, t = idx & 4095;
        const int hh = 1 << lh;
        const int j = t & (hh - 1);
        double s, c;
        sincos(-PI_D * (double)j / (double)hh, &s, &c);
        twid[idx] = make_float2((float)c, (float)s);
    } else {
        idx -= 13 * 4096;
        if (idx < 6 * 3072) {
            const int s = idx / 3072;
            const int r = idx - s * 3072;
            const int j = r / 3;
            const int m = r - 3 * j + 1;
            const int q = 1024 >> (2 * s);
            double sn, cs;
            sincos(-2.0 * PI_D * (double)(m * (j & (q - 1))) / (double)(4 * q), &sn, &cs);
            tw4[idx] = make_float2((float)cs, (float)sn);
        }
    }
}

// ---------------------------------------------------------------------------
// Merged split: three fp32 arrays -> (hi, lo) bf16 arrays in one launch
// ---------------------------------------------------------------------------
__global__ __launch_bounds__(256) void kern_split3(
        const float* __restrict__ s0, ushort_t* __restrict__ h0, ushort_t* __restrict__ l0, int n0,
        const float* __restrict__ s1, ushort_t* __restrict__ h1, ushort_t* __restrict__ l1, int n1,
        const float* __restrict__ s2, ushort_t* __restrict__ h2, ushort_t* __restrict__ l2, int n2) {
    int i = blockIdx.x * 256 + threadIdx.x;
    const float* s; ushort_t* hh; ushort_t* ll; int k;
    if (i < n0)                { s = s0; hh = h0; ll = l0; k = i; }
    else if (i < n0 + n1)      { s = s1; hh = h1; ll = l1; k = i - n0; }
    else if (i < n0 + n1 + n2) { s = s2; hh = h2; ll = l2; k = i - n0 - n1; }
    else return;
    ushort_t h, l;
    split_bf16(s[k], h, l);
    hh[k] = h; ll[k] = l;
}

// ---------------------------------------------------------------------------
// Split-bf16 MFMA NT GEMM: C = A*B^T + bias. 3 cross-products.
// 128x128 tile, BK=32, 256 thr. M, Nn, K multiples of 128.
// ---------------------------------------------------------------------------
__global__ __launch_bounds__(256) void gemm_mfma(
        const ushort_t* __restrict__ Ah, const ushort_t* __restrict__ Al, int lda,
        const ushort_t* __restrict__ Bh, const ushort_t* __restrict__ Bl, int ldb,
        const float* __restrict__ bias, float* __restrict__ C,
        int Nn, int K) {
    __shared__ __align__(16) ushort_t At0[128 * 32];
    __shared__ __align__(16) ushort_t At1[128 * 32];
    __shared__ __align__(16) ushort_t Bt0[128 * 32];
    __shared__ __align__(16) ushort_t Bt1[128 * 32];

    const int tid = threadIdx.x;
    const int wv = tid >> 6, lane = tid & 63;
    const int quad = lane >> 4, lrow = lane & 15;
    const int m0 = blockIdx.y * 128, n0 = blockIdx.x * 128;
    const int mw = (wv >> 1) * 64, nw = (wv & 1) * 64;

    const int srow = lane >> 2;
    const int schunk = (lane & 3) * 8;

    f32x4 acc[4][4] = {};

    for (int k0 = 0; k0 < K; k0 += 32) {
        {
            const size_t ga = (size_t)(m0 + wv * 32 + srow) * lda + k0 + schunk;
            const size_t gb = (size_t)(n0 + wv * 32 + srow) * ldb + k0 + schunk;
            const size_t ga2 = ga + (size_t)16 * lda;
            const size_t gb2 = gb + (size_t)16 * ldb;
            GLD16(Ah + ga,  &At0[(wv * 32) * 32]);
            GLD16(Ah + ga2, &At0[(wv * 32 + 16) * 32]);
            GLD16(Al + ga,  &At1[(wv * 32) * 32]);
            GLD16(Al + ga2, &At1[(wv * 32 + 16) * 32]);
            GLD16(Bh + gb,  &Bt0[(wv * 32) * 32]);
            GLD16(Bh + gb2, &Bt0[(wv * 32 + 16) * 32]);
            GLD16(Bl + gb,  &Bt1[(wv * 32) * 32]);
            GLD16(Bl + gb2, &Bt1[(wv * 32 + 16) * 32]);
        }
        __syncthreads();

        bf16x8 a0[4], a1[4], b0[4], b1[4];
#pragma unroll
        for (int i = 0; i < 4; ++i) {
            a0[i] = *(const bf16x8*)&At0[(mw + i * 16 + lrow) * 32 + quad * 8];
            a1[i] = *(const bf16x8*)&At1[(mw + i * 16 + lrow) * 32 + quad * 8];
            b0[i] = *(const bf16x8*)&Bt0[(nw + i * 16 + lrow) * 32 + quad * 8];
            b1[i] = *(const bf16x8*)&Bt1[(nw + i * 16 + lrow) * 32 + quad * 8];
        }
#pragma unroll
        for (int mi = 0; mi < 4; ++mi)
#pragma unroll
            for (int nj = 0; nj < 4; ++nj) {
                acc[mi][nj] = __builtin_amdgcn_mfma_f32_16x16x32_bf16(a0[mi], b0[nj], acc[mi][nj], 0, 0, 0);
                acc[mi][nj] = __builtin_amdgcn_mfma_f32_16x16x32_bf16(a0[mi], b1[nj], acc[mi][nj], 0, 0, 0);
                acc[mi][nj] = __builtin_amdgcn_mfma_f32_16x16x32_bf16(a1[mi], b0[nj], acc[mi][nj], 0, 0, 0);
            }
        __syncthreads();
    }

#pragma unroll
    for (int mi = 0; mi < 4; ++mi) {
        const int row = m0 + mw + mi * 16 + quad * 4;
#pragma unroll
        for (int nj = 0; nj < 4; ++nj) {
            const int col = n0 + nw + nj * 16 + lrow;
            const float bv = bias[col];
#pragma unroll
            for (int r = 0; r < 4; ++r)
                C[(size_t)(row + r) * Nn + col] = acc[mi][nj][r] + bv;
        }
    }
}

// ---------------------------------------------------------------------------
// M=4 GEMV for the control path: C[m,col] = act(sum_k A[m,k]*W[col,k]+bias).
// One wave per column; K=1024; lanes stride k; shuffle reduce.
// ---------------------------------------------------------------------------
__device__ __forceinline__ float gelu_f(float x) {
    return 0.5f * x * (1.f + tanhf(0.7978845608028654f * (x + 0.044715f * x * x * x)));
}

__global__ __launch_bounds__(256) void kern_gemv4(const float* __restrict__ A,
                                                  const float* __restrict__ W,
                                                  const float* __restrict__ bias,
                                                  float* __restrict__ C,
                                                  int Nn, int act) {
    const int tid = threadIdx.x;
    const int wv = tid >> 6, lane = tid & 63;
    const int col = blockIdx.x * 4 + wv;
    const float* wp = W + (size_t)col * D_;
    float a0 = 0.f, a1 = 0.f, a2 = 0.f, a3 = 0.f;
#pragma unroll
    for (int i = 0; i < 16; ++i) {
        int k = lane + i * 64;
        float w = wp[k];
        a0 += A[k] * w;
        a1 += A[D_ + k] * w;
        a2 += A[2 * D_ + k] * w;
        a3 += A[3 * D_ + k] * w;
    }
    for (int m = 1; m < 64; m <<= 1) {
        a0 += __shfl_xor(a0, m);
        a1 += __shfl_xor(a1, m);
        a2 += __shfl_xor(a2, m);
        a3 += __shfl_xor(a3, m);
    }
    if (lane == 0) {
        float bv = bias[col];
        float v0 = a0 + bv, v1 = a1 + bv, v2 = a2 + bv, v3 = a3 + bv;
        if (act) { v0 = gelu_f(v0); v1 = gelu_f(v1); v2 = gelu_f(v2); v3 = gelu_f(v3); }
        C[0 * Nn + col] = v0;
        C[1 * Nn + col] = v1;
        C[2 * Nn + col] = v2;
        C[3 * Nn + col] = v3;
    }
}

// ---------------------------------------------------------------------------
// Featuremap + field build. Tiles padded to [68] (16B-aligned rows) for
// float4 broadcast LDS reads; wbuf stays [65] (transposed store pattern).
// ---------------------------------------------------------------------------
__global__ __launch_bounds__(256) void kern_feat(float* __restrict__ qkvg,
                                                 const float* __restrict__ qfm_w,
                                                 const float* __restrict__ qfm_b,
                                                 const float* __restrict__ kfm_w,
                                                 const float* __restrict__ kfm_b,
                                                 const float* __restrict__ wg_w,
                                                 const float* __restrict__ wg_b,
                                                 float* __restrict__ field) {
    __shared__ __align__(16) float in_t[64][68];
    __shared__ __align__(16) float tmp[64][68];
    __shared__ float wbuf[64][65];
    __shared__ float bsm[64];
    __shared__ float wsm[64];
    __shared__ float wgbuf[64];

    const int tid = threadIdx.x;
    const int lane = tid & 63, grp = tid >> 6;
    const int n0 = blockIdx.x * 64;
    const int h = blockIdx.y, b = blockIdx.z;
    const size_t rowbase = (size_t)(b * N_ + n0) * 4096;

    const int lr4 = tid >> 4;          // 0..15 row within 16-row group
    const int lc4 = (tid & 15) * 4;    // 0,4,...,60 col

#define LOAD64x64(dst, off) \
    for (int it = 0; it < 4; ++it) { \
        int r = lr4 + it * 16; \
        float4 v = *(const float4*)&qkvg[rowbase + (size_t)r * 4096 + (off) + lc4]; \
        *(float4*)&dst[r][lc4] = v; \
    }

#define MLP_LAYER(dstarr, srcarr) { \
    const int j = lane, ibase = grp * 16; \
    float acc[16]; \
    _Pragma("unroll") for (int ii = 0; ii < 16; ++ii) acc[ii] = 0.f; \
    for (int c4 = 0; c4 < 64; c4 += 4) { \
        float w0 = wbuf[c4 + 0][j], w1 = wbuf[c4 + 1][j]; \
        float w2 = wbuf[c4 + 2][j], w3 = wbuf[c4 + 3][j]; \
        _Pragma("unroll") for (int ii = 0; ii < 16; ++ii) { \
            float4 iv = *(const float4*)&srcarr[ibase + ii][c4]; \
            acc[ii] += iv.x * w0 + iv.y * w1 + iv.z * w2 + iv.w * w3; \
        } \
    } \
    float bj = bsm[j]; \
    _Pragma("unroll") for (int ii = 0; ii < 16; ++ii) \
        dstarr[ibase + ii][j] = fmaxf(acc[ii] + bj, 0.f); \
    }

    // ============ K path ============
    LOAD64x64(in_t, D_ + h * 64)
    for (int it = 0; it < 16; ++it) {
        int r = grp + 4 * it;
        wbuf[lane][r] = kfm_w[(size_t)r * 64 + lane];   // wbuf[c][j] = W0[j][c]
    }
    if (tid < 64) { bsm[tid] = kfm_b[tid]; wsm[tid] = wg_w[tid]; }
    __syncthreads();
    if (tid < 64) {   // wg from raw k
        float s = 0.f;
        for (int c4 = 0; c4 < 64; c4 += 4) {
            float4 iv = *(const float4*)&in_t[tid][c4];
            s += iv.x * wsm[c4] + iv.y * wsm[c4 + 1] + iv.z * wsm[c4 + 2] + iv.w * wsm[c4 + 3];
        }
        s += wg_b[0];
        wgbuf[tid] = 1.f / (1.f + expf(-s));
    }
    MLP_LAYER(tmp, in_t)
    __syncthreads();
    for (int it = 0; it < 16; ++it) {
        int r = grp + 4 * it;
        wbuf[lane][r] = kfm_w[(size_t)(64 + r) * 64 + lane];
    }
    if (tid < 64) bsm[tid] = kfm_b[64 + tid];
    __syncthreads();
    {   // L2: phi_k -> in_t (+EPS)
        const int j = lane, ibase = grp * 16;
        float acc[16];
#pragma unroll
        for (int ii = 0; ii < 16; ++ii) acc[ii] = 0.f;
        for (int c4 = 0; c4 < 64; c4 += 4) {
            float w0 = wbuf[c4 + 0][j], w1 = wbuf[c4 + 1][j];
            float w2 = wbuf[c4 + 2][j], w3 = wbuf[c4 + 3][j];
#pragma unroll
            for (int ii = 0; ii < 16; ++ii) {
                float4 iv = *(const float4*)&tmp[ibase + ii][c4];
                acc[ii] += iv.x * w0 + iv.y * w1 + iv.z * w2 + iv.w * w3;
            }
        }
        float bj = bsm[j];
#pragma unroll
        for (int ii = 0; ii < 16; ++ii)
            in_t[ibase + ii][j] = fmaxf(acc[ii] + bj, 0.f) + EPS_;
    }
    __syncthreads();
    LOAD64x64(tmp, 2 * D_ + h * 64)     // V -> tmp
    __syncthreads();

    // field write: write[c<64] = wg*pk*v ; write[c>=64] = wg*pk
    {
        float* frow = field + (size_t)(b * H_ + h) * 128 * F_;
        const bool last = (n0 == N_ - 64);
        for (int c = grp; c < 128; c += 4) {
            int i = lane;
            float v = (c < 64) ? wgbuf[i] * in_t[i][c] * tmp[i][c]
                               : wgbuf[i] * in_t[i][c - 64];
            if (last) {
                if (i == 62) {
                    float v2 = (c < 64) ? wgbuf[63] * in_t[63][c] * tmp[63][c]
                                        : wgbuf[63] * in_t[63][c - 64];
                    v += v2;
                } else if (i == 63) v = 0.f;
            }
            frow[(size_t)c * F_ + n0 + i] = v;
        }
    }
    __syncthreads();

    // ============ Q path ============
    LOAD64x64(in_t, h * 64)
    for (int it = 0; it < 16; ++it) {
        int r = grp + 4 * it;
        wbuf[lane][r] = qfm_w[(size_t)r * 64 + lane];
    }
    if (tid < 64) bsm[tid] = qfm_b[tid];
    __syncthreads();
    MLP_LAYER(tmp, in_t)
    __syncthreads();
    for (int it = 0; it < 16; ++it) {
        int r = grp + 4 * it;
        wbuf[lane][r] = qfm_w[(size_t)(64 + r) * 64 + lane];
    }
    if (tid < 64) bsm[tid] = qfm_b[64 + tid];
    __syncthreads();
    {   // L2: phi_q -> qkvg k-columns
        const int j = lane, ibase = grp * 16;
        float acc[16];
#pragma unroll
        for (int ii = 0; ii < 16; ++ii) acc[ii] = 0.f;
        for (int c4 = 0; c4 < 64; c4 += 4) {
            float w0 = wbuf[c4 + 0][j], w1 = wbuf[c4 + 1][j];
            float w2 = wbuf[c4 + 2][j], w3 = wbuf[c4 + 3][j];
#pragma unroll
            for (int ii = 0; ii < 16; ++ii) {
                float4 iv = *(const float4*)&tmp[ibase + ii][c4];
                acc[ii] += iv.x * w0 + iv.y * w1 + iv.z * w2 + iv.w * w3;
            }
        }
        float bj = bsm[j];
#pragma unroll
        for (int ii = 0; ii < 16; ++ii) {
            float v = fmaxf(acc[ii] + bj, 0.f) + EPS_;
            qkvg[rowbase + (size_t)(ibase + ii) * 4096 + D_ + h * 64 + j] = v;
        }
    }
#undef LOAD64x64
#undef MLP_LAYER
}

// ---------------------------------------------------------------------------
// LayerNorm of q token 0 -> q0n (B x 1024).
// ---------------------------------------------------------------------------
__global__ void kern_ln(const float* __restrict__ qkvg,
                        const float* __restrict__ ln_g,
                        const float* __restrict__ ln_b,
                        float* __restrict__ q0n) {
    const int bh = blockIdx.x, c = threadIdx.x;
    const int b = bh >> 4, h = bh & 15;
    float x = qkvg[(size_t)(b * N_) * 4096 + h * 64 + c];
    float mu = x;
    for (int m = 1; m < 64; m <<= 1) mu += __shfl_xor(mu, m);
    mu *= (1.f / 64.f);
    float dv = (x - mu) * (x - mu);
    for (int m = 1; m < 64; m <<= 1) dv += __shfl_xor(dv, m);
    float var = dv * (1.f / 64.f);
    q0n[b * 1024 + h * 64 + c] = (x - mu) * rsqrtf(var + 1e-5f) * ln_g[c] + ln_b[c];
}

// ---------------------------------------------------------------------------
// Templated table-driven FFT helpers (NT = threads per block).
// ---------------------------------------------------------------------------
template <int NT>
__device__ __forceinline__ void fft_fwd_dif_t(float* xr, float* xi, int tid, int logn,
                                              const float2* __restrict__ twid) {
    const int nb = 1 << (logn - 1);
    for (int lh = logn - 1; lh >= 0; --lh) {
        const int hh = 1 << lh;
        const float2* tws = twid + lh * 4096;
        for (int t = tid; t < nb; t += NT) {
            int j = t & (hh - 1);
            int i1 = ((t >> lh) << (lh + 1)) | j;
            int i2 = i1 + hh;
            float2 tw = tws[t];
            float ar = xr[i1], ai = xi[i1];
            float br = xr[i2], bi = xi[i2];
            xr[i1] = ar + br; xi[i1] = ai + bi;
            float tr = ar - br, ti = ai - bi;
            xr[i2] = tr * tw.x - ti * tw.y;
            xi[i2] = tr * tw.y + ti * tw.x;
        }
        __syncthreads();
    }
}

template <int NT>
__device__ __forceinline__ void fft_inv_dit_t(float* xr, float* xi, int tid, int logn,
                                              const float2* __restrict__ twid) {
    const int nb = 1 << (logn - 1);
    for (int lh = 0; lh < logn; ++lh) {
        const int hh = 1 << lh;
        const float2* tws = twid + lh * 4096;
        for (int t = tid; t < nb; t += NT) {
            int j = t & (hh - 1);
            int i1 = ((t >> lh) << (lh + 1)) | j;
            int i2 = i1 + hh;
            float2 tw = tws[t];   // conj applied
            float br = xr[i2], bi = xi[i2];
            float tr = br * tw.x + bi * tw.y;
            float ti = bi * tw.x - br * tw.y;
            float ar = xr[i1], ai = xi[i1];
            xr[i1] = ar + tr; xi[i1] = ai + ti;
            xr[i2] = ar - tr; xi[i2] = ai - ti;
        }
        __syncthreads();
    }
}

template <int NT>
__device__ __forceinline__ void fft4_fwd(float2* z, int tid,
                                         const float2* __restrict__ tw4) {
#pragma unroll
    for (int s = 0; s < 6; ++s) {
        const int q = 1024 >> (2 * s);
        const float2* tws = tw4 + s * 3072;
        for (int t = tid; t < 1024; t += NT) {
            int j = t & (q - 1);
            int base = ((t & ~(q - 1)) << 2) | j;
            float2 a = z[base], b = z[base + q], c = z[base + 2 * q], d = z[base + 3 * q];
            float2 s0 = make_float2(a.x + c.x, a.y + c.y);
            float2 s1 = make_float2(a.x - c.x, a.y - c.y);
            float2 s2 = make_float2(b.x + d.x, b.y + d.y);
            float2 s3 = make_float2(b.x - d.x, b.y - d.y);
            float2 m1 = make_float2(s1.x + s3.y, s1.y - s3.x);
            float2 m2 = make_float2(s0.x - s2.x, s0.y - s2.y);
            float2 m3 = make_float2(s1.x - s3.y, s1.y + s3.x);
            z[base]         = make_float2(s0.x + s2.x, s0.y + s2.y);
            z[base + q]     = cmul(m1, tws[3 * j + 0]);
            z[base + 2 * q] = cmul(m2, tws[3 * j + 1]);
            z[base + 3 * q] = cmul(m3, tws[3 * j + 2]);
        }
        __syncthreads();
    }
}

template <int NT>
__device__ __forceinline__ void fft4_inv(float2* z, int tid,
                                         const float2* __restrict__ tw4) {
#pragma unroll
    for (int s = 5; s >= 0; --s) {
        const int q = 1024 >> (2 * s);
        const float2* tws = tw4 + s * 3072;
        for (int t = tid; t < 1024; t += NT) {
            int j = t & (q - 1);
            int base = ((t & ~(q - 1)) << 2) | j;
            float2 a = z[base];
            float2 b = cmulc(z[base + q],     tws[3 * j + 0]);
            float2 c = cmulc(z[base + 2 * q], tws[3 * j + 1]);
            float2 d = cmulc(z[base + 3 * q], tws[3 * j + 2]);
            float2 p0 = make_float2(a.x + c.x, a.y + c.y);
            float2 p1 = make_float2(a.x - c.x, a.y - c.y);
            float2 p2 = make_float2(b.x + d.x, b.y + d.y);
            float2 p3 = make_float2(b.x - d.x, b.y - d.y);
            z[base]         = make_float2(p0.x + p2.x, p0.y + p2.y);
            z[base + q]     = make_float2(p1.x - p3.y, p1.y + p3.x);
            z[base + 2 * q] = make_float2(p0.x - p2.x, p0.y - p2.y);
            z[base + 3 * q] = make_float2(p1.x + p3.y, p1.y - p3.x);
        }
        __syncthreads();
    }
}

// ---------------------------------------------------------------------------
// Merged prep (1024 threads, per (b,h)): build damped-cosine kernel, fwd 8192
// FFT, apply gate in BR order, inv FFT, fold to 4096, radix-4 fwd -> GBR.
// ---------------------------------------------------------------------------
__global__ __launch_bounds__(1024) void kern_prep(const float* __restrict__ freq,
                                                  const float* __restrict__ damp,
                                                  const float* __restrict__ phase,
                                                  const float* __restrict__ ctrl,
                                                  const float2* __restrict__ twid,
                                                  const float2* __restrict__ tw4,
                                                  float* __restrict__ GBR) {
    __shared__ float sm[2 * PAD_];    // 64 KB
    float* xr = sm;
    float* xi = sm + PAD_;
    const int bh = blockIdx.x, tid = threadIdx.x;
    const int b = bh >> 4, h = bh & 15;

    // build kernel in time domain
    const float fr = freq[h], ed = expf(damp[h]), ph = phase[h];
    for (int f = tid; f < PAD_; f += 1024) {
        float v = 0.f;
        if (f < F_) {
            float t = (float)f / (float)F_;
            v = expf(-ed * t) * cosf(fr * t + ph);
        }
        xr[f] = v; xi[f] = 0.f;
    }
    __syncthreads();
    fft_fwd_dif_t<1024>(xr, xi, tid, 13, twid);   // natural -> BR spectrum

    // gate in BR order
    const float* cp = ctrl + b * (H_ * NC_) + h * NC_;
    for (int j = tid; j < PAD_; j += 1024) {
        int k = (int)(__brev((unsigned)j) >> 19);
        int kk = min(k, PAD_ - k);
        float ip = (float)kk * ((float)(NC_ - 1) / (float)(FB_ - 1));
        int il = min((int)ip, NC_ - 2);
        float iw = ip - (float)il;
        float m = 1.f + cp[il] * (1.f - iw) + cp[il + 1] * iw;
        xr[j] *= m;
        xi[j] *= m;
    }
    __syncthreads();
    fft_inv_dit_t<1024>(xr, xi, tid, 13, twid);   // BR -> natural keff (unscaled)

    // fold to 4096 real kernel, staged through registers
    float g[4];
    const float sc = 1.f / (float)PAD_;
#pragma unroll
    for (int u = 0; u < 4; ++u) {
        int j = tid + u * 1024;
        g[u] = ((j < 2048) ? xr[j] : xr[j + 4096]) * sc;
    }
    __syncthreads();
    float2* z = (float2*)sm;
#pragma unroll
    for (int u = 0; u < 4; ++u) {
        int j = tid + u * 1024;
        z[j] = make_float2(g[u], 0.f);
    }
    __syncthreads();
    fft4_fwd<1024>(z, tid, tw4);                  // natural -> digit-reversed
    for (int j = tid; j < 4096; j += 1024) {
        GBR[((size_t)bh * 4096 + j) * 2 + 0] = z[j].x;
        GBR[((size_t)bh * 4096 + j) * 2 + 1] = z[j].y;
    }
}

// Main conv: 4096-pt radix-4 complex FFT, 2 real channels packed per block.
// 512 threads: 2 butterflies/thread/stage.
__global__ __launch_bounds__(512) void kern_conv4(float* __restrict__ field,
                                                  const float* __restrict__ GBR,
                                                  const float2* __restrict__ tw4) {
    __shared__ float2 z[4096];
    const int tid = threadIdx.x;
    const int bh = blockIdx.x >> 6, cp = blockIdx.x & 63;
    float* rowx = field + ((size_t)bh * 128 + 2 * cp) * F_;
    float* rowy = rowx + F_;

    for (int f = tid; f < 2048; f += 512) {
        z[f] = make_float2(rowx[f], rowy[f]);
        z[f + 2048] = make_float2(0.f, 0.f);
    }
    __syncthreads();

    fft4_fwd<512>(z, tid, tw4);

    {
        const float2* G = (const float2*)(GBR) + (size_t)bh * 4096;
        for (int j = tid; j < 4096; j += 512)
            z[j] = cmul(z[j], G[j]);
    }
    __syncthreads();

    fft4_inv<512>(z, tid, tw4);

    const float s = 1.f / 4096.f;
    for (int f = tid; f < 2048; f += 512) {
        float2 v = z[f];
        rowx[f] = v.x * s;
        rowy[f] = v.y * s;
    }
}

// combine WITH fused coupling, line-preserving layout:
// block = (b, 16 consecutive tokens, ALL h). wave wv = token n, lane = c.
// Each 64B field line (16 f-values) is fully consumed by the block's 16 waves.
// y[h,c] = sum_g coup[h,g]*conv[b,g,c,f]; out -> bf16 hi/lo in qkvg q-cols.
__global__ __launch_bounds__(1024) void kern_combine(float* __restrict__ qkvg,
                                                     const float* __restrict__ field,
                                                     const float* __restrict__ coupling) {
    __shared__ float cpl[16][16];
    const int tid = threadIdx.x;
    if (tid < 256) cpl[tid >> 4][tid & 15] = coupling[tid];
    __syncthreads();
    const int lane = tid & 63, wv = tid >> 6;
    const int n = blockIdx.x * 16 + wv;
    const int b = blockIdx.y;
    const int f = min(n, F_ - 2);
    const size_t row = (size_t)(b * N_ + n) * 4096;

    // gather the 16 g-plane values for this (c, f) — num (c) and den (64+c)
    float cN[16], cD[16];
#pragma unroll
    for (int g = 0; g < 16; ++g) {
        const float* cv = field + (size_t)(b * 16 + g) * 128 * F_;
        cN[g] = cv[(size_t)lane * F_ + f];
        cD[g] = cv[(size_t)(64 + lane) * F_ + f];
    }

    ushort_t* rp = (ushort_t*)(qkvg + row);
#pragma unroll
    for (int h = 0; h < 16; ++h) {
        float ynum = 0.f, yden = 0.f;
#pragma unroll
        for (int g = 0; g < 16; ++g) {
            float cg = cpl[h][g];
            ynum += cg * cN[g];
            yden += cg * cD[g];
        }
        float pq = qkvg[row + D_ + h * 64 + lane];
        float gv = qkvg[row + 3 * D_ + h * 64 + lane];
        float s = pq * yden;
        for (int m = 1; m < 64; m <<= 1) s += __shfl_xor(s, m);
        float den = fabsf(s) + 1e-4f;
        float o = pq * ynum / den * (1.f / (1.f + expf(-gv)));
        ushort_t oh, ol;
        split_bf16(o, oh, ol);
        rp[h * 64 + lane] = oh;
        rp[1024 + h * 64 + lane] = ol;
    }
}

// ---------------------------------------------------------------------------
extern "C" void kernel_launch(void* const* d_in, const int* in_sizes, int n_in,
                              void* d_out, int out_size, void* d_ws, size_t ws_size,
                              hipStream_t stream) {
    const float* x      = (const float*)d_in[0];
    const float* w_qkvg = (const float*)d_in[1];
    const float* b_qkvg = (const float*)d_in[2];
    const float* w_out  = (const float*)d_in[3];
    const float* b_out  = (const float*)d_in[4];
    const float* qfm_w  = (const float*)d_in[5];
    const float* qfm_b  = (const float*)d_in[6];
    const float* kfm_w  = (const float*)d_in[7];
    const float* kfm_b  = (const float*)d_in[8];
    const float* wg_w   = (const float*)d_in[9];
    const float* wg_b   = (const float*)d_in[10];
    const float* ln_g   = (const float*)d_in[11];
    const float* ln_b   = (const float*)d_in[12];
    const float* sg_w1  = (const float*)d_in[13];
    const float* sg_b1  = (const float*)d_in[14];
    const float* sg_w2  = (const float*)d_in[15];
    const float* sg_b2  = (const float*)d_in[16];
    const float* wfreq  = (const float*)d_in[17];
    const float* wdamp  = (const float*)d_in[18];
    const float* wphase = (const float*)d_in[19];
    const float* coup   = (const float*)d_in[20];

    float* ws = (float*)d_ws;
    // workspace (floats):
    float*  qkvg   = ws;                 // 33,554,432
    float*  field  = ws + 33554432;      // 16,777,216
    float*  GBR    = ws + 50593792;      //    524,288
    float2* twid   = (float2*)(ws + 51118080);   // 106,496 floats (radix-2)
    float*  q0n    = ws + 51224576;      //      4,096
    float*  h1     = ws + 51228672;      //      4,096
    float*  ctrl   = ws + 51232768;      //      2,048
    ushort_t* wouth = (ushort_t*)(ws + 51234816); // 524,288 floats
    ushort_t* woutl = (ushort_t*)(ws + 51759104); // 524,288 floats
    float2* tw4    = (float2*)(ws + 52283392);    // 36,864 floats (radix-4)
    // end: 52,320,256 floats = 209.3 MB

    // bf16 staging aliases inside `field` (consumed by gemm#1 before feat writes)
    ushort_t* xh  = (ushort_t*)(field);
    ushort_t* xl  = (ushort_t*)(field + 4194304);
    ushort_t* wqh = (ushort_t*)(field + 8388608);
    ushort_t* wql = (ushort_t*)(field + 10485760);

    // 0. twiddles (merged) + splits (merged)
    kern_twid<<<(13 * 4096 + 6 * 3072) / 256, 256, 0, stream>>>(twid, tw4);
    kern_split3<<<(B_ * N_ * D_ + 4 * D_ * D_ + D_ * D_) / 256, 256, 0, stream>>>(
        x, xh, xl, B_ * N_ * D_,
        w_qkvg, wqh, wql, 4 * D_ * D_,
        w_out, wouth, woutl, D_ * D_);

    // 1. qkvg = x @ w_qkvg^T + b_qkvg   (split-bf16 MFMA)
    gemm_mfma<<<dim3(4096 / 128, 8192 / 128), 256, 0, stream>>>(
        xh, xl, D_, wqh, wql, D_, b_qkvg, qkvg, 4 * D_, D_);

    // 2. control path: LN + two M=4 GEMVs
    kern_ln<<<B_ * H_, 64, 0, stream>>>(qkvg, ln_g, ln_b, q0n);
    kern_gemv4<<<D_ / 4, 256, 0, stream>>>(q0n, sg_w1, sg_b1, h1, D_, 1);
    kern_gemv4<<<(H_ * NC_) / 4, 256, 0, stream>>>(h1, sg_w2, sg_b2, ctrl, H_ * NC_, 0);

    // 3. spectra prep (merged base FFT + gate + fold, 1024 thr)
    kern_prep<<<B_ * H_, 1024, 0, stream>>>(wfreq, wdamp, wphase, ctrl, twid, tw4, GBR);

    // 4. featmaps + wg + field build
    kern_feat<<<dim3(N_ / 64, H_, B_), 256, 0, stream>>>(
        qkvg, qfm_w, qfm_b, kfm_w, kfm_b, wg_w, wg_b, field);

    // 5. FFT convolution (radix-4, 512 thr, in place on field)
    kern_conv4<<<B_ * H_ * 64, 512, 0, stream>>>(field, GBR, tw4);

    // 6. combine (+fused coupling, line-preserving) -> qkvg q-columns
    kern_combine<<<dim3(N_ / 16, B_), 1024, 0, stream>>>(qkvg, field, coup);

    // 7. out = att @ w_out^T + b_out
    gemm_mfma<<<dim3(1024 / 128, 8192 / 128), 256, 0, stream>>>(
        (ushort_t*)qkvg, (ushort_t*)qkvg + 1024, 8192,
        wouth, woutl, D_, b_out, (float*)d_out, D_, D_);
}